// Round 13
// baseline (756.497 us; speedup 1.0000x reference)
//
#include <hip/hip_runtime.h>
#include <math.h>

#define B 128
#define N 512
#define M 512
#define D 128

typedef __attribute__((ext_vector_type(8))) short s16x8;
typedef __attribute__((ext_vector_type(4))) short s16x4;
typedef __attribute__((ext_vector_type(4))) float f32x4;

#define MFMA16(a, b, c) __builtin_amdgcn_mfma_f32_16x16x32_bf16(a, b, c, 0, 0, 0)

#define FENCE()   asm volatile("" ::: "memory")
#define VMCNT4()  asm volatile("s_waitcnt vmcnt(4)" ::: "memory")
#define VMCNT8()  asm volatile("s_waitcnt vmcnt(8)" ::: "memory")
#define VMCNT12() asm volatile("s_waitcnt vmcnt(12)" ::: "memory")
#define VMCNT16() asm volatile("s_waitcnt vmcnt(16)" ::: "memory")
#define VMCNT20() asm volatile("s_waitcnt vmcnt(20)" ::: "memory")
#define LGKMCNT0() asm volatile("s_waitcnt lgkmcnt(0)" ::: "memory")
#define SCHEDBAR() __builtin_amdgcn_sched_barrier(0)

__device__ __forceinline__ void gload16(const void* g, void* l) {
    __builtin_amdgcn_global_load_lds(
        (const __attribute__((address_space(1))) unsigned int*)g,
        (__attribute__((address_space(3))) unsigned int*)l, 16, 0, 0);
}

__device__ __forceinline__ float fast_tanh(float x) {
    x = fminf(fmaxf(x, -15.f), 15.f);
    float E = __expf(2.f * x);
    return 1.f - 2.f / (E + 1.f);
}

__device__ __forceinline__ unsigned short bf16rne(float x) {
    unsigned u = __float_as_uint(x);
    return (unsigned short)((u + 0x7FFF + ((u >> 16) & 1)) >> 16);
}

__device__ __forceinline__ void fsplit(float x, short& h, short& l) {
    unsigned u = __float_as_uint(x);
    h = (short)(u >> 16);
    float fh = __uint_as_float(u & 0xffff0000u);
    l = (short)(__float_as_uint(x - fh) >> 16);
}

__device__ __forceinline__ void fsplit8(float4 x0, float4 x1, s16x8& h, s16x8& l) {
    short a, b;
    fsplit(x0.x, a, b); h[0] = a; l[0] = b;
    fsplit(x0.y, a, b); h[1] = a; l[1] = b;
    fsplit(x0.z, a, b); h[2] = a; l[2] = b;
    fsplit(x0.w, a, b); h[3] = a; l[3] = b;
    fsplit(x1.x, a, b); h[4] = a; l[4] = b;
    fsplit(x1.y, a, b); h[5] = a; l[5] = b;
    fsplit(x1.z, a, b); h[6] = a; l[6] = b;
    fsplit(x1.w, a, b); h[7] = a; l[7] = b;
}

// EB = exp(-a1ls*cd + ninf) -> single bf16 RNE
__device__ __forceinline__ void ebpack(float4 c0, float4 c1, float4 f0, float4 f1,
                                       float a1ls, s16x8& a) {
    a[0] = (short)bf16rne(__expf(fmaf(-a1ls, c0.x, f0.x)));
    a[1] = (short)bf16rne(__expf(fmaf(-a1ls, c0.y, f0.y)));
    a[2] = (short)bf16rne(__expf(fmaf(-a1ls, c0.z, f0.z)));
    a[3] = (short)bf16rne(__expf(fmaf(-a1ls, c0.w, f0.w)));
    a[4] = (short)bf16rne(__expf(fmaf(-a1ls, c1.x, f1.x)));
    a[5] = (short)bf16rne(__expf(fmaf(-a1ls, c1.y, f1.y)));
    a[6] = (short)bf16rne(__expf(fmaf(-a1ls, c1.z, f1.z)));
    a[7] = (short)bf16rne(__expf(fmaf(-a1ls, c1.w, f1.w)));
}

__global__ void k_prep_w(const float* __restrict__ Wk, const float* __restrict__ Wv,
                         const float* __restrict__ Wq,
                         unsigned short* __restrict__ Wk_hi, unsigned short* __restrict__ Wk_lo,
                         unsigned short* __restrict__ Wv_hi, unsigned short* __restrict__ Wv_lo,
                         unsigned short* __restrict__ Wq_hi, unsigned short* __restrict__ Wq_lo) {
    int i = blockIdx.x * 256 + threadIdx.x;  // 0..49151
    short h, l;
    if (i < 16384) {
        fsplit(Wk[i], h, l); Wk_hi[i] = (unsigned short)h; Wk_lo[i] = (unsigned short)l;
    } else if (i < 32768) {
        int j = i - 16384;
        fsplit(Wv[j], h, l); Wv_hi[j] = (unsigned short)h; Wv_lo[j] = (unsigned short)l;
    } else {
        int j = i - 32768; int e = j >> 7, d = j & 127;
        fsplit(Wq[e * 129 + d], h, l); Wq_hi[j] = (unsigned short)h; Wq_lo[j] = (unsigned short)l;
    }
}

// k = enc@Wk^T, v = enc@Wv^T; store bf16-RNE EK, EK*V as [b][e][m],
// SWIZZLED: within each 32-m group, 8-m chunk c stored at c ^ (e&3).
__global__ __launch_bounds__(256) void k_kv(const float* __restrict__ enc,
        const unsigned short* __restrict__ Wk_hi, const unsigned short* __restrict__ Wk_lo,
        const unsigned short* __restrict__ Wv_hi, const unsigned short* __restrict__ Wv_lo,
        unsigned short* __restrict__ EKb, unsigned short* __restrict__ EKVb) {
    int b = blockIdx.y;
    int wave = threadIdx.x >> 6, lane = threadIdx.x & 63;
    int row = lane & 15, kg = lane >> 4;
    int m0 = blockIdx.x * 64 + wave * 16;
    f32x4 acc[16];
#pragma unroll
    for (int i = 0; i < 16; i++) acc[i] = (f32x4)0.f;
    const float* ap = enc + ((size_t)b * M + m0 + row) * D + kg * 8;
#pragma unroll
    for (int ks = 0; ks < 4; ks++) {
        float4 x0 = *(const float4*)(ap + ks * 32);
        float4 x1 = *(const float4*)(ap + ks * 32 + 4);
        s16x8 ah, al;
        fsplit8(x0, x1, ah, al);
        int wb = ks * 32 + kg * 8;
#pragma unroll
        for (int ct = 0; ct < 8; ct++) {
            int e = ct * 16 + row;
            s16x8 bh = *(const s16x8*)(Wk_hi + e * D + wb);
            s16x8 bl = *(const s16x8*)(Wk_lo + e * D + wb);
            acc[ct] = MFMA16(ah, bh, acc[ct]);
            acc[ct] = MFMA16(al, bh, acc[ct]);
            acc[ct] = MFMA16(ah, bl, acc[ct]);
            bh = *(const s16x8*)(Wv_hi + e * D + wb);
            bl = *(const s16x8*)(Wv_lo + e * D + wb);
            acc[8 + ct] = MFMA16(ah, bh, acc[8 + ct]);
            acc[8 + ct] = MFMA16(al, bh, acc[8 + ct]);
            acc[8 + ct] = MFMA16(ah, bl, acc[8 + ct]);
        }
    }
#pragma unroll
    for (int ct = 0; ct < 8; ct++) {
        int e = ct * 16 + row;
        s16x4 kb, vb;
#pragma unroll
        for (int r = 0; r < 4; r++) {
            float ek = __expf(acc[ct][r]);
            float ev = ek * acc[8 + ct][r];
            kb[r] = (short)bf16rne(ek);
            vb[r] = (short)bf16rne(ev);
        }
        int m = m0 + kg * 4;
        int chunk = (m & 31) >> 3;
        int p = chunk ^ (e & 3);
        size_t o = ((size_t)b * D + e) * M + (size_t)(m & ~31) + p * 8 + (m & 7);
        *(s16x4*)(EKb + o) = kb;
        *(s16x4*)(EKVb + o) = vb;
    }
}

// Pack enc -> single bf16-RNE [b][m][128e], SWIZZLED: 8-e chunk c at c ^ (m&7)
__global__ void k_encpack(const float* __restrict__ enc, unsigned short* __restrict__ Eb) {
    size_t i = (size_t)blockIdx.x * 256 + threadIdx.x;   // chunk id
    size_t bm = i >> 4;
    int c = (int)(i & 15);
    int m = (int)(bm & 511);
    int p = c ^ (m & 7);
    const float* src = enc + bm * 128 + c * 8;
    float4 x0 = *(const float4*)(src);
    float4 x1 = *(const float4*)(src + 4);
    s16x8 v;
    v[0] = (short)bf16rne(x0.x); v[1] = (short)bf16rne(x0.y);
    v[2] = (short)bf16rne(x0.z); v[3] = (short)bf16rne(x0.w);
    v[4] = (short)bf16rne(x1.x); v[5] = (short)bf16rne(x1.y);
    v[6] = (short)bf16rne(x1.z); v[7] = (short)bf16rne(x1.w);
    *(s16x8*)(Eb + bm * 128 + p * 8) = v;
}

// MEGA-FUSED, barrier-free main loops; wave-private staging; LDS exactly 32 KB
// (redm/reds + aafm bounce aliased into the wave buffers, barrier-guarded).
__global__ __launch_bounds__(256, 5) void k_fused(
        const float* __restrict__ encl, const float* __restrict__ loadv,
        const float* __restrict__ Wq,
        const unsigned short* __restrict__ Wq_hi, const unsigned short* __restrict__ Wq_lo,
        const float* __restrict__ cd, const float* __restrict__ ninf,
        const unsigned short* __restrict__ EKVb, const unsigned short* __restrict__ EKb,
        const unsigned short* __restrict__ Eb,
        const float* __restrict__ a1p, const float* __restrict__ a2p,
        const float* __restrict__ lsp, float* __restrict__ out) {
    int o = blockIdx.x;
    int xcd = o & 7, j = o >> 3;       // j 0..255
    int b = ((j >> 4) << 3) + xcd;     // 16 b's per XCD
    int nb = j & 15;
    int n0 = nb * 32;
    int w = threadIdx.x >> 6, lane = threadIdx.x & 63;
    int row = lane & 15, kg = lane >> 4;
    __shared__ __align__(16) char lds[32768];   // wave-private: wave w owns [w*8K, +8K)
    float* redm = (float*)lds;                  // aliased; used only after D bufs die
    float* reds = (float*)(lds + 512);
    float a1ls = a1p[0] * lsp[0];
    float a2ls = a2p[0] * lsp[0];
    const float invs = 0.08838834764831845f;  // 1/sqrt(128)
    char* wb = lds + w * 8192;                // 2 bufs x 4 KB

    // ===== Phase A: q-pass; sq = sigmoid(q) in regs (e = w*32 + ct*16 + row) =====
    f32x4 sqa[2][2];
#pragma unroll
    for (int s = 0; s < 2; s++)
#pragma unroll
        for (int ct = 0; ct < 2; ct++) sqa[s][ct] = (f32x4)0.f;
#pragma unroll
    for (int s = 0; s < 2; s++) {
        const float* ap = encl + ((size_t)b * N + n0 + s * 16 + row) * D + kg * 8;
#pragma unroll
        for (int ks = 0; ks < 4; ks++) {
            float4 x0 = *(const float4*)(ap + ks * 32);
            float4 x1 = *(const float4*)(ap + ks * 32 + 4);
            s16x8 ah, al;
            fsplit8(x0, x1, ah, al);
            int wqo = ks * 32 + kg * 8;
#pragma unroll
            for (int ct = 0; ct < 2; ct++) {
                int e = w * 32 + ct * 16 + row;
                s16x8 bh = *(const s16x8*)(Wq_hi + e * D + wqo);
                s16x8 bl = *(const s16x8*)(Wq_lo + e * D + wqo);
                sqa[s][ct] = MFMA16(ah, bh, sqa[s][ct]);
                sqa[s][ct] = MFMA16(al, bh, sqa[s][ct]);
                sqa[s][ct] = MFMA16(ah, bl, sqa[s][ct]);
            }
        }
    }
    float sqv[2][2][4];
#pragma unroll
    for (int s = 0; s < 2; s++)
#pragma unroll
        for (int ct = 0; ct < 2; ct++) {
            int e = w * 32 + ct * 16 + row;
            float wcol = Wq[e * 129 + 128];
#pragma unroll
            for (int r = 0; r < 4; r++) {
                int n = n0 + s * 16 + kg * 4 + r;
                float q = sqa[s][ct][r] + loadv[(size_t)b * N + n] * wcol;
                sqv[s][ct][r] = 1.f / (1.f + __expf(-q));
            }
        }
    FENCE();   // pin all phase-A vmem before the B ledger starts

    // ===== Phase B: num/den, wave-private e-slice [w*32, w*32+32) =====
    f32x4 accN[2][2], accD[2][2];
#pragma unroll
    for (int s = 0; s < 2; s++)
#pragma unroll
        for (int i = 0; i < 2; i++) { accN[s][i] = (f32x4)0.f; accD[s][i] = (f32x4)0.f; }
    const char* gEKV = (const char*)EKVb + (size_t)b * D * M * 2;
    const char* gEK  = (const char*)EKb  + (size_t)b * D * M * 2;
    const float* cdp0 = cd + ((size_t)b * N + n0 + row) * M + kg * 8;
    const float* nfp0 = ninf + ((size_t)b * N + n0 + row) * M + kg * 8;
    const float* cdp1 = cdp0 + (size_t)16 * M;
    const float* nfp1 = nfp0 + (size_t)16 * M;

// stage wave's 4 KB slice of tile mt into bufptr: [2 arr][32 e][64 B]
#define STAGE_B(bufptr, mt)                                                      \
    _Pragma("unroll")                                                            \
    for (int jv = 0; jv < 4; jv++) {                                             \
        int arr = jv >> 1;                                                       \
        int rem = (jv & 1) * 64 + lane;                                          \
        const char* gb = arr ? gEK : gEKV;                                       \
        gload16(gb + (size_t)(w * 32 + (rem >> 2)) * 1024 + (size_t)(mt) * 64 +  \
                    (rem & 3) * 16,                                              \
                (char*)(bufptr) + arr * 2048 + rem * 16);                        \
    }

    float4 Ac[2][2][2], Af[2][2][2];   // [parity][n-set][half]
#define LOAD_A(p, mt)                                                            \
    Ac[p][0][0] = *(const float4*)(cdp0 + (mt) * 32);                            \
    Ac[p][0][1] = *(const float4*)(cdp0 + (mt) * 32 + 4);                        \
    Af[p][0][0] = *(const float4*)(nfp0 + (mt) * 32);                            \
    Af[p][0][1] = *(const float4*)(nfp0 + (mt) * 32 + 4);                        \
    Ac[p][1][0] = *(const float4*)(cdp1 + (mt) * 32);                            \
    Ac[p][1][1] = *(const float4*)(cdp1 + (mt) * 32 + 4);                        \
    Af[p][1][0] = *(const float4*)(nfp1 + (mt) * 32);                            \
    Af[p][1][1] = *(const float4*)(nfp1 + (mt) * 32 + 4);

    // prologue order (fenced): A0, S0, A1, S1
    LOAD_A(0, 0) FENCE();
    STAGE_B(wb, 0) FENCE();
    LOAD_A(1, 1) FENCE();
    STAGE_B(wb + 4096, 1) FENCE();

    int rbB = row * 64 + ((kg ^ (row & 3)) << 4);
#pragma unroll
    for (int mt = 0; mt < 16; mt++) {
        // W(t): younger-than-S(t) = {t<2: 12 ; 2..14: A(t)8+S(t+1)4+A(t+1)8 = 20 ; 15: 8}
        if (mt < 2) { VMCNT12(); } else if (mt < 15) { VMCNT20(); } else { VMCNT8(); }
        SCHEDBAR();
        int p = mt & 1;
        s16x8 a0, a1;
        ebpack(Ac[p][0][0], Ac[p][0][1], Af[p][0][0], Af[p][0][1], a1ls, a0);
        ebpack(Ac[p][1][0], Ac[p][1][1], Af[p][1][0], Af[p][1][1], a1ls, a1);
        const char* L = wb + p * 4096;
#pragma unroll
        for (int ct = 0; ct < 2; ct++) {
            int ro = ct * 1024 + rbB;
            s16x8 bv = *(const s16x8*)(L + ro);           // EKV
            s16x8 bk = *(const s16x8*)(L + 2048 + ro);    // EK
            accN[0][ct] = MFMA16(a0, bv, accN[0][ct]);
            accN[1][ct] = MFMA16(a1, bv, accN[1][ct]);
            accD[0][ct] = MFMA16(a0, bk, accD[0][ct]);
            accD[1][ct] = MFMA16(a1, bk, accD[1][ct]);
        }
        if (mt <= 13) {
            LGKMCNT0();   // own ds_reads of this buffer done -> safe to restage
            SCHEDBAR();
            STAGE_B(wb + p * 4096, mt + 2) FENCE();
            LOAD_A(p, mt + 2) FENCE();
        }
    }

    // ===== Phase C: aafm = sq*nan_to_num(num/den), single bf16-RNE bounce =====
    __syncthreads();   // all waves done with B buffers
    unsigned short* af = (unsigned short*)lds;   // 8 KB: [32 n][128 e] bf16
#pragma unroll
    for (int s = 0; s < 2; s++)
#pragma unroll
        for (int ct = 0; ct < 2; ct++) {
            int e = w * 32 + ct * 16 + row;
#pragma unroll
            for (int r = 0; r < 4; r++) {
                int nl = s * 16 + kg * 4 + r;
                float num = accN[s][ct][r], den = accD[s][ct][r];
                float ww = (den != 0.f) ? num / den : 0.f;
                af[nl * 128 + e] = bf16rne(sqv[s][ct][r] * ww);
            }
        }
    __syncthreads();
    s16x8 afr[2][4];   // A-frags for score: [n-set][es]
#pragma unroll
    for (int s = 0; s < 2; s++)
#pragma unroll
        for (int es = 0; es < 4; es++)
            afr[s][es] = *(const s16x8*)(af + (s * 16 + row) * 128 + es * 32 + kg * 8);
    __syncthreads();   // af dead; lds reused by wave-private D staging
    FENCE();

    // ===== Phase D: score, wave-private m-quarter [w*128, w*128+128) =====
    // acc[s][p]: n = n0 + s*16 + kg*4 + r ; m = w*128 + p*16 + row
    f32x4 acc[2][8];
#pragma unroll
    for (int s = 0; s < 2; s++)
#pragma unroll
        for (int p = 0; p < 8; p++) acc[s][p] = (f32x4)0.f;
    const char* gEb = (const char*)Eb + (size_t)b * M * 256;

// stage wave's 4 KB (16 m x 256 B) of tile p into bufptr
#define STAGE_D(bufptr, p)                                                       \
    _Pragma("unroll")                                                            \
    for (int jv = 0; jv < 4; jv++) {                                             \
        int id = jv * 64 + lane;                                                 \
        gload16(gEb + (size_t)(w * 128 + (p) * 16 + (id >> 4)) * 256 + (id & 15) * 16, \
                (char*)(bufptr) + id * 16);                                      \
    }

    // prologue (fenced): S0, S1; A loads are depth-1 in-loop (cd/ninf L2-hot)
    STAGE_D(wb, 0) FENCE();
    STAGE_D(wb + 4096, 1) FENCE();

#pragma unroll
    for (int p = 0; p < 8; p++) {
        // W(p): younger-than-S(p) = {0: S1 = 4 ; 1..6: A(p-1)16 + S(p+1)4 = 20 ; 7: A(6) = 16}
        if (p == 0) { VMCNT4(); } else if (p < 7) { VMCNT20(); } else { VMCNT16(); }
        SCHEDBAR();
        // this phase's cd/ninf (L2-hot from phase B) — used after MFMA
        float cdv[2][4], nfv[2][4];
#pragma unroll
        for (int s = 0; s < 2; s++)
#pragma unroll
            for (int r = 0; r < 4; r++) {
                size_t idx = ((size_t)b * N + n0 + s * 16 + kg * 4 + r) * M
                           + (size_t)w * 128 + (size_t)p * 16 + row;
                cdv[s][r] = cd[idx];
                nfv[s][r] = ninf[idx];
            }
        FENCE();
        const char* L = wb + (p & 1) * 4096;
        int sw = row & 7;
#pragma unroll
        for (int es = 0; es < 4; es++) {
            int ph = (4 * es + kg) ^ sw;
            s16x8 bb = *(const s16x8*)(L + row * 256 + ph * 16);
            acc[0][p] = MFMA16(afr[0][es], bb, acc[0][p]);
            acc[1][p] = MFMA16(afr[1][es], bb, acc[1][p]);
        }
        if (p <= 5) {
            LGKMCNT0();
            SCHEDBAR();
            STAGE_D(wb + (p & 1) * 4096, p + 2) FENCE();
        }
        // bias + tanh + mask
#pragma unroll
        for (int s = 0; s < 2; s++)
#pragma unroll
            for (int r = 0; r < 4; r++) {
                acc[s][p][r] = 10.f * fast_tanh(fmaf(acc[s][p][r], invs, -a2ls * cdv[s][r]))
                             + nfv[s][r];
            }
    }

    // ===== softmax over m (in-lane p, row-lanes, then 4 wave quarters) =====
    __syncthreads();   // D buffers dead; redm/reds region (aliased) now safe
    float mx[2][4], sm[2][4];
#pragma unroll
    for (int s = 0; s < 2; s++)
#pragma unroll
        for (int r = 0; r < 4; r++) {
            float m = acc[s][0][r];
#pragma unroll
            for (int p = 1; p < 8; p++) m = fmaxf(m, acc[s][p][r]);
#pragma unroll
            for (int sh = 1; sh < 16; sh <<= 1) m = fmaxf(m, __shfl_xor(m, sh, 64));
            mx[s][r] = m;
        }
    if (row == 0) {
#pragma unroll
        for (int s = 0; s < 2; s++)
#pragma unroll
            for (int r = 0; r < 4; r++) redm[(s * 16 + kg * 4 + r) * 4 + w] = mx[s][r];
    }
    __syncthreads();
#pragma unroll
    for (int s = 0; s < 2; s++)
#pragma unroll
        for (int r = 0; r < 4; r++) {
            int nl = s * 16 + kg * 4 + r;
            float m = fmaxf(fmaxf(redm[nl * 4 + 0], redm[nl * 4 + 1]),
                            fmaxf(redm[nl * 4 + 2], redm[nl * 4 + 3]));
            float sum = 0.f;
#pragma unroll
            for (int p = 0; p < 8; p++) {
                float e = __expf(acc[s][p][r] - m);
                acc[s][p][r] = e;
                sum += e;
            }
#pragma unroll
            for (int sh = 1; sh < 16; sh <<= 1) sum += __shfl_xor(sum, sh, 64);
            sm[s][r] = sum;
        }
    if (row == 0) {
#pragma unroll
        for (int s = 0; s < 2; s++)
#pragma unroll
            for (int r = 0; r < 4; r++) reds[(s * 16 + kg * 4 + r) * 4 + w] = sm[s][r];
    }
    __syncthreads();
#pragma unroll
    for (int s = 0; s < 2; s++)
#pragma unroll
        for (int r = 0; r < 4; r++) {
            int nl = s * 16 + kg * 4 + r;
            float inv = 1.f / (reds[nl * 4 + 0] + reds[nl * 4 + 1]
                             + reds[nl * 4 + 2] + reds[nl * 4 + 3]);
            size_t ro = ((size_t)b * N + n0 + nl) * M + (size_t)w * 128 + row;
#pragma unroll
            for (int p = 0; p < 8; p++) {
                out[ro + p * 16] = acc[s][p][r] * inv;
            }
        }
}

extern "C" void kernel_launch(void* const* d_in, const int* in_sizes, int n_in,
                              void* d_out, int out_size, void* d_ws, size_t ws_size,
                              hipStream_t stream) {
    const float* encl  = (const float*)d_in[0];
    const float* loadv = (const float*)d_in[1];
    const float* cdist = (const float*)d_in[2];
    const float* ls    = (const float*)d_in[3];
    const float* ninf  = (const float*)d_in[4];
    const float* enc   = (const float*)d_in[5];
    const float* Wq    = (const float*)d_in[6];
    const float* Wk    = (const float*)d_in[7];
    const float* Wv    = (const float*)d_in[8];
    const float* a1    = (const float*)d_in[9];
    const float* a2    = (const float*)d_in[10];
    char* ws = (char*)d_ws;
    unsigned short* EKb     = (unsigned short*)(ws);                    // 16.8 MB
    unsigned short* EKVb    = (unsigned short*)(ws + 16777216);         // 16.8 MB
    unsigned short* Eb      = (unsigned short*)(ws + 33554432);         // 16.8 MB
    unsigned short* Wk_hi   = (unsigned short*)(ws + 50331648);
    unsigned short* Wk_lo   = (unsigned short*)(ws + 50331648 + 32768);
    unsigned short* Wv_hi   = (unsigned short*)(ws + 50331648 + 65536);
    unsigned short* Wv_lo   = (unsigned short*)(ws + 50331648 + 98304);
    unsigned short* Wq_hi   = (unsigned short*)(ws + 50331648 + 131072);
    unsigned short* Wq_lo   = (unsigned short*)(ws + 50331648 + 163840);
    float* out = (float*)d_out;

    k_prep_w<<<192, 256, 0, stream>>>(Wk, Wv, Wq, Wk_hi, Wk_lo, Wv_hi, Wv_lo, Wq_hi, Wq_lo);
    k_kv<<<dim3(8, 128), 256, 0, stream>>>(enc, Wk_hi, Wk_lo, Wv_hi, Wv_lo, EKb, EKVb);
    k_encpack<<<4096, 256, 0, stream>>>(enc, Eb);
    k_fused<<<2048, 256, 0, stream>>>(encl, loadv, Wq, Wq_hi, Wq_lo,
                                      cdist, ninf, EKVb, EKb, Eb,
                                      a1, a2, ls, out);
}

// Round 14
// 393.537 us; speedup vs baseline: 1.9223x; 1.9223x over previous
//
#include <hip/hip_runtime.h>
#include <math.h>

#define B 128
#define N 512
#define M 512
#define D 128

typedef __attribute__((ext_vector_type(8))) short s16x8;
typedef __attribute__((ext_vector_type(4))) short s16x4;
typedef __attribute__((ext_vector_type(4))) float f32x4;

#define MFMA16(a, b, c) __builtin_amdgcn_mfma_f32_16x16x32_bf16(a, b, c, 0, 0, 0)

#define FENCE()   asm volatile("" ::: "memory")
#define VMCNT4()  asm volatile("s_waitcnt vmcnt(4)" ::: "memory")
#define VMCNT8()  asm volatile("s_waitcnt vmcnt(8)" ::: "memory")
#define VMCNT12() asm volatile("s_waitcnt vmcnt(12)" ::: "memory")
#define VMCNT16() asm volatile("s_waitcnt vmcnt(16)" ::: "memory")
#define VMCNT20() asm volatile("s_waitcnt vmcnt(20)" ::: "memory")
#define LGKMCNT0() asm volatile("s_waitcnt lgkmcnt(0)" ::: "memory")
#define SCHEDBAR() __builtin_amdgcn_sched_barrier(0)

__device__ __forceinline__ void gload16(const void* g, void* l) {
    __builtin_amdgcn_global_load_lds(
        (const __attribute__((address_space(1))) unsigned int*)g,
        (__attribute__((address_space(3))) unsigned int*)l, 16, 0, 0);
}

__device__ __forceinline__ float fast_tanh(float x) {
    x = fminf(fmaxf(x, -15.f), 15.f);
    float E = __expf(2.f * x);
    return 1.f - 2.f / (E + 1.f);
}

__device__ __forceinline__ unsigned short bf16rne(float x) {
    unsigned u = __float_as_uint(x);
    return (unsigned short)((u + 0x7FFF + ((u >> 16) & 1)) >> 16);
}

__device__ __forceinline__ void fsplit(float x, short& h, short& l) {
    unsigned u = __float_as_uint(x);
    h = (short)(u >> 16);
    float fh = __uint_as_float(u & 0xffff0000u);
    l = (short)(__float_as_uint(x - fh) >> 16);
}

__device__ __forceinline__ void fsplit8(float4 x0, float4 x1, s16x8& h, s16x8& l) {
    short a, b;
    fsplit(x0.x, a, b); h[0] = a; l[0] = b;
    fsplit(x0.y, a, b); h[1] = a; l[1] = b;
    fsplit(x0.z, a, b); h[2] = a; l[2] = b;
    fsplit(x0.w, a, b); h[3] = a; l[3] = b;
    fsplit(x1.x, a, b); h[4] = a; l[4] = b;
    fsplit(x1.y, a, b); h[5] = a; l[5] = b;
    fsplit(x1.z, a, b); h[6] = a; l[6] = b;
    fsplit(x1.w, a, b); h[7] = a; l[7] = b;
}

// EB = exp(-a1ls*cd + ninf) -> single bf16 RNE
__device__ __forceinline__ void ebpack(float4 c0, float4 c1, float4 f0, float4 f1,
                                       float a1ls, s16x8& a) {
    a[0] = (short)bf16rne(__expf(fmaf(-a1ls, c0.x, f0.x)));
    a[1] = (short)bf16rne(__expf(fmaf(-a1ls, c0.y, f0.y)));
    a[2] = (short)bf16rne(__expf(fmaf(-a1ls, c0.z, f0.z)));
    a[3] = (short)bf16rne(__expf(fmaf(-a1ls, c0.w, f0.w)));
    a[4] = (short)bf16rne(__expf(fmaf(-a1ls, c1.x, f1.x)));
    a[5] = (short)bf16rne(__expf(fmaf(-a1ls, c1.y, f1.y)));
    a[6] = (short)bf16rne(__expf(fmaf(-a1ls, c1.z, f1.z)));
    a[7] = (short)bf16rne(__expf(fmaf(-a1ls, c1.w, f1.w)));
}

__global__ void k_prep_w(const float* __restrict__ Wk, const float* __restrict__ Wv,
                         const float* __restrict__ Wq,
                         unsigned short* __restrict__ Wk_hi, unsigned short* __restrict__ Wk_lo,
                         unsigned short* __restrict__ Wv_hi, unsigned short* __restrict__ Wv_lo,
                         unsigned short* __restrict__ Wq_hi, unsigned short* __restrict__ Wq_lo) {
    int i = blockIdx.x * 256 + threadIdx.x;  // 0..49151
    short h, l;
    if (i < 16384) {
        fsplit(Wk[i], h, l); Wk_hi[i] = (unsigned short)h; Wk_lo[i] = (unsigned short)l;
    } else if (i < 32768) {
        int j = i - 16384;
        fsplit(Wv[j], h, l); Wv_hi[j] = (unsigned short)h; Wv_lo[j] = (unsigned short)l;
    } else {
        int j = i - 32768; int e = j >> 7, d = j & 127;
        fsplit(Wq[e * 129 + d], h, l); Wq_hi[j] = (unsigned short)h; Wq_lo[j] = (unsigned short)l;
    }
}

// k = enc@Wk^T, v = enc@Wv^T; store bf16-RNE EK, EK*V as [b][e][m],
// SWIZZLED: within each 32-m group, 8-m chunk c stored at c ^ (e&3).
__global__ __launch_bounds__(256) void k_kv(const float* __restrict__ enc,
        const unsigned short* __restrict__ Wk_hi, const unsigned short* __restrict__ Wk_lo,
        const unsigned short* __restrict__ Wv_hi, const unsigned short* __restrict__ Wv_lo,
        unsigned short* __restrict__ EKb, unsigned short* __restrict__ EKVb) {
    int b = blockIdx.y;
    int wave = threadIdx.x >> 6, lane = threadIdx.x & 63;
    int row = lane & 15, kg = lane >> 4;
    int m0 = blockIdx.x * 64 + wave * 16;
    f32x4 acc[16];
#pragma unroll
    for (int i = 0; i < 16; i++) acc[i] = (f32x4)0.f;
    const float* ap = enc + ((size_t)b * M + m0 + row) * D + kg * 8;
#pragma unroll
    for (int ks = 0; ks < 4; ks++) {
        float4 x0 = *(const float4*)(ap + ks * 32);
        float4 x1 = *(const float4*)(ap + ks * 32 + 4);
        s16x8 ah, al;
        fsplit8(x0, x1, ah, al);
        int wb = ks * 32 + kg * 8;
#pragma unroll
        for (int ct = 0; ct < 8; ct++) {
            int e = ct * 16 + row;
            s16x8 bh = *(const s16x8*)(Wk_hi + e * D + wb);
            s16x8 bl = *(const s16x8*)(Wk_lo + e * D + wb);
            acc[ct] = MFMA16(ah, bh, acc[ct]);
            acc[ct] = MFMA16(al, bh, acc[ct]);
            acc[ct] = MFMA16(ah, bl, acc[ct]);
            bh = *(const s16x8*)(Wv_hi + e * D + wb);
            bl = *(const s16x8*)(Wv_lo + e * D + wb);
            acc[8 + ct] = MFMA16(ah, bh, acc[8 + ct]);
            acc[8 + ct] = MFMA16(al, bh, acc[8 + ct]);
            acc[8 + ct] = MFMA16(ah, bl, acc[8 + ct]);
        }
    }
#pragma unroll
    for (int ct = 0; ct < 8; ct++) {
        int e = ct * 16 + row;
        s16x4 kb, vb;
#pragma unroll
        for (int r = 0; r < 4; r++) {
            float ek = __expf(acc[ct][r]);
            float ev = ek * acc[8 + ct][r];
            kb[r] = (short)bf16rne(ek);
            vb[r] = (short)bf16rne(ev);
        }
        int m = m0 + kg * 4;
        int chunk = (m & 31) >> 3;
        int p = chunk ^ (e & 3);
        size_t o = ((size_t)b * D + e) * M + (size_t)(m & ~31) + p * 8 + (m & 7);
        *(s16x4*)(EKb + o) = kb;
        *(s16x4*)(EKVb + o) = vb;
    }
}

// Pack enc -> single bf16-RNE [b][m][128e], SWIZZLED: 8-e chunk c at c ^ (m&7)
__global__ void k_encpack(const float* __restrict__ enc, unsigned short* __restrict__ Eb) {
    size_t i = (size_t)blockIdx.x * 256 + threadIdx.x;   // chunk id
    size_t bm = i >> 4;
    int c = (int)(i & 15);
    int m = (int)(bm & 511);
    int p = c ^ (m & 7);
    const float* src = enc + bm * 128 + c * 8;
    float4 x0 = *(const float4*)(src);
    float4 x1 = *(const float4*)(src + 4);
    s16x8 v;
    v[0] = (short)bf16rne(x0.x); v[1] = (short)bf16rne(x0.y);
    v[2] = (short)bf16rne(x0.z); v[3] = (short)bf16rne(x0.w);
    v[4] = (short)bf16rne(x1.x); v[5] = (short)bf16rne(x1.y);
    v[6] = (short)bf16rne(x1.z); v[7] = (short)bf16rne(x1.w);
    *(s16x8*)(Eb + bm * 128 + p * 8) = v;
}

// MEGA-FUSED, barrier-free main loops; wave-private staging; LDS exactly 32 KB.
// launch_bounds(256,4): VGPR budget 128 (kernel needs ~85) -> no spill, 4 blocks/CU.
__global__ __launch_bounds__(256, 4) void k_fused(
        const float* __restrict__ encl, const float* __restrict__ loadv,
        const float* __restrict__ Wq,
        const unsigned short* __restrict__ Wq_hi, const unsigned short* __restrict__ Wq_lo,
        const float* __restrict__ cd, const float* __restrict__ ninf,
        const unsigned short* __restrict__ EKVb, const unsigned short* __restrict__ EKb,
        const unsigned short* __restrict__ Eb,
        const float* __restrict__ a1p, const float* __restrict__ a2p,
        const float* __restrict__ lsp, float* __restrict__ out) {
    int o = blockIdx.x;
    int xcd = o & 7, j = o >> 3;       // j 0..255
    int b = ((j >> 4) << 3) + xcd;     // 16 b's per XCD
    int nb = j & 15;
    int n0 = nb * 32;
    int w = threadIdx.x >> 6, lane = threadIdx.x & 63;
    int row = lane & 15, kg = lane >> 4;
    __shared__ __align__(16) char lds[32768];   // wave-private: wave w owns [w*8K, +8K)
    float* redm = (float*)lds;                  // aliased; used only after D bufs die
    float* reds = (float*)(lds + 512);
    float a1ls = a1p[0] * lsp[0];
    float a2ls = a2p[0] * lsp[0];
    const float invs = 0.08838834764831845f;  // 1/sqrt(128)
    char* wb = lds + w * 8192;                // 2 bufs x 4 KB

    // ===== Phase A: q-pass; sq = sigmoid(q) in regs (e = w*32 + ct*16 + row) =====
    f32x4 sqa[2][2];
#pragma unroll
    for (int s = 0; s < 2; s++)
#pragma unroll
        for (int ct = 0; ct < 2; ct++) sqa[s][ct] = (f32x4)0.f;
#pragma unroll
    for (int s = 0; s < 2; s++) {
        const float* ap = encl + ((size_t)b * N + n0 + s * 16 + row) * D + kg * 8;
#pragma unroll
        for (int ks = 0; ks < 4; ks++) {
            float4 x0 = *(const float4*)(ap + ks * 32);
            float4 x1 = *(const float4*)(ap + ks * 32 + 4);
            s16x8 ah, al;
            fsplit8(x0, x1, ah, al);
            int wqo = ks * 32 + kg * 8;
#pragma unroll
            for (int ct = 0; ct < 2; ct++) {
                int e = w * 32 + ct * 16 + row;
                s16x8 bh = *(const s16x8*)(Wq_hi + e * D + wqo);
                s16x8 bl = *(const s16x8*)(Wq_lo + e * D + wqo);
                sqa[s][ct] = MFMA16(ah, bh, sqa[s][ct]);
                sqa[s][ct] = MFMA16(al, bh, sqa[s][ct]);
                sqa[s][ct] = MFMA16(ah, bl, sqa[s][ct]);
            }
        }
    }
    float sqv[2][2][4];
#pragma unroll
    for (int s = 0; s < 2; s++)
#pragma unroll
        for (int ct = 0; ct < 2; ct++) {
            int e = w * 32 + ct * 16 + row;
            float wcol = Wq[e * 129 + 128];
#pragma unroll
            for (int r = 0; r < 4; r++) {
                int n = n0 + s * 16 + kg * 4 + r;
                float q = sqa[s][ct][r] + loadv[(size_t)b * N + n] * wcol;
                sqv[s][ct][r] = 1.f / (1.f + __expf(-q));
            }
        }
    FENCE();   // pin all phase-A vmem before the B ledger starts

    // ===== Phase B: num/den, wave-private e-slice [w*32, w*32+32) =====
    f32x4 accN[2][2], accD[2][2];
#pragma unroll
    for (int s = 0; s < 2; s++)
#pragma unroll
        for (int i = 0; i < 2; i++) { accN[s][i] = (f32x4)0.f; accD[s][i] = (f32x4)0.f; }
    const char* gEKV = (const char*)EKVb + (size_t)b * D * M * 2;
    const char* gEK  = (const char*)EKb  + (size_t)b * D * M * 2;
    const float* cdp0 = cd + ((size_t)b * N + n0 + row) * M + kg * 8;
    const float* nfp0 = ninf + ((size_t)b * N + n0 + row) * M + kg * 8;
    const float* cdp1 = cdp0 + (size_t)16 * M;
    const float* nfp1 = nfp0 + (size_t)16 * M;

// stage wave's 4 KB slice of tile mt into bufptr: [2 arr][32 e][64 B]
#define STAGE_B(bufptr, mt)                                                      \
    _Pragma("unroll")                                                            \
    for (int jv = 0; jv < 4; jv++) {                                             \
        int arr = jv >> 1;                                                       \
        int rem = (jv & 1) * 64 + lane;                                          \
        const char* gb = arr ? gEK : gEKV;                                       \
        gload16(gb + (size_t)(w * 32 + (rem >> 2)) * 1024 + (size_t)(mt) * 64 +  \
                    (rem & 3) * 16,                                              \
                (char*)(bufptr) + arr * 2048 + rem * 16);                        \
    }

    float4 Ac[2][2][2], Af[2][2][2];   // [parity][n-set][half]
#define LOAD_A(p, mt)                                                            \
    Ac[p][0][0] = *(const float4*)(cdp0 + (mt) * 32);                            \
    Ac[p][0][1] = *(const float4*)(cdp0 + (mt) * 32 + 4);                        \
    Af[p][0][0] = *(const float4*)(nfp0 + (mt) * 32);                            \
    Af[p][0][1] = *(const float4*)(nfp0 + (mt) * 32 + 4);                        \
    Ac[p][1][0] = *(const float4*)(cdp1 + (mt) * 32);                            \
    Ac[p][1][1] = *(const float4*)(cdp1 + (mt) * 32 + 4);                        \
    Af[p][1][0] = *(const float4*)(nfp1 + (mt) * 32);                            \
    Af[p][1][1] = *(const float4*)(nfp1 + (mt) * 32 + 4);

    // prologue order (fenced): A0, S0, A1, S1
    LOAD_A(0, 0) FENCE();
    STAGE_B(wb, 0) FENCE();
    LOAD_A(1, 1) FENCE();
    STAGE_B(wb + 4096, 1) FENCE();

    int rbB = row * 64 + ((kg ^ (row & 3)) << 4);
#pragma unroll
    for (int mt = 0; mt < 16; mt++) {
        // W(t): younger-than-S(t) = {t<2: 12 ; 2..14: A(t)8+S(t+1)4+A(t+1)8 = 20 ; 15: 8}
        if (mt < 2) { VMCNT12(); } else if (mt < 15) { VMCNT20(); } else { VMCNT8(); }
        SCHEDBAR();
        int p = mt & 1;
        s16x8 a0, a1;
        ebpack(Ac[p][0][0], Ac[p][0][1], Af[p][0][0], Af[p][0][1], a1ls, a0);
        ebpack(Ac[p][1][0], Ac[p][1][1], Af[p][1][0], Af[p][1][1], a1ls, a1);
        const char* L = wb + p * 4096;
#pragma unroll
        for (int ct = 0; ct < 2; ct++) {
            int ro = ct * 1024 + rbB;
            s16x8 bv = *(const s16x8*)(L + ro);           // EKV
            s16x8 bk = *(const s16x8*)(L + 2048 + ro);    // EK
            accN[0][ct] = MFMA16(a0, bv, accN[0][ct]);
            accN[1][ct] = MFMA16(a1, bv, accN[1][ct]);
            accD[0][ct] = MFMA16(a0, bk, accD[0][ct]);
            accD[1][ct] = MFMA16(a1, bk, accD[1][ct]);
        }
        if (mt <= 13) {
            LGKMCNT0();   // own ds_reads of this buffer done -> safe to restage
            SCHEDBAR();
            STAGE_B(wb + p * 4096, mt + 2) FENCE();
            LOAD_A(p, mt + 2) FENCE();
        }
    }

    // ===== Phase C: aafm = sq*nan_to_num(num/den), single bf16-RNE bounce =====
    __syncthreads();   // all waves done with B buffers
    unsigned short* af = (unsigned short*)lds;   // 8 KB: [32 n][128 e] bf16
#pragma unroll
    for (int s = 0; s < 2; s++)
#pragma unroll
        for (int ct = 0; ct < 2; ct++) {
            int e = w * 32 + ct * 16 + row;
#pragma unroll
            for (int r = 0; r < 4; r++) {
                int nl = s * 16 + kg * 4 + r;
                float num = accN[s][ct][r], den = accD[s][ct][r];
                float ww = (den != 0.f) ? num / den : 0.f;
                af[nl * 128 + e] = bf16rne(sqv[s][ct][r] * ww);
            }
        }
    __syncthreads();
    s16x8 afr[2][4];   // A-frags for score: [n-set][es]
#pragma unroll
    for (int s = 0; s < 2; s++)
#pragma unroll
        for (int es = 0; es < 4; es++)
            afr[s][es] = *(const s16x8*)(af + (s * 16 + row) * 128 + es * 32 + kg * 8);
    __syncthreads();   // af dead; lds reused by wave-private D staging
    FENCE();

    // ===== Phase D: score, wave-private m-quarter [w*128, w*128+128) =====
    // acc[s][p]: n = n0 + s*16 + kg*4 + r ; m = w*128 + p*16 + row
    f32x4 acc[2][8];
#pragma unroll
    for (int s = 0; s < 2; s++)
#pragma unroll
        for (int p = 0; p < 8; p++) acc[s][p] = (f32x4)0.f;
    const char* gEb = (const char*)Eb + (size_t)b * M * 256;

// stage wave's 4 KB (16 m x 256 B) of tile p into bufptr
#define STAGE_D(bufptr, p)                                                       \
    _Pragma("unroll")                                                            \
    for (int jv = 0; jv < 4; jv++) {                                             \
        int id = jv * 64 + lane;                                                 \
        gload16(gEb + (size_t)(w * 128 + (p) * 16 + (id >> 4)) * 256 + (id & 15) * 16, \
                (char*)(bufptr) + id * 16);                                      \
    }

    // prologue (fenced): S0, S1; A loads are depth-1 in-loop (cd/ninf L2-hot)
    STAGE_D(wb, 0) FENCE();
    STAGE_D(wb + 4096, 1) FENCE();

#pragma unroll
    for (int p = 0; p < 8; p++) {
        // W(p): younger-than-S(p) = {0: S1 = 4 ; 1..6: A(p-1)16 + S(p+1)4 = 20 ; 7: A(6) = 16}
        if (p == 0) { VMCNT4(); } else if (p < 7) { VMCNT20(); } else { VMCNT16(); }
        SCHEDBAR();
        // this phase's cd/ninf (L2-hot from phase B) — used after MFMA
        float cdv[2][4], nfv[2][4];
#pragma unroll
        for (int s = 0; s < 2; s++)
#pragma unroll
            for (int r = 0; r < 4; r++) {
                size_t idx = ((size_t)b * N + n0 + s * 16 + kg * 4 + r) * M
                           + (size_t)w * 128 + (size_t)p * 16 + row;
                cdv[s][r] = cd[idx];
                nfv[s][r] = ninf[idx];
            }
        FENCE();
        const char* L = wb + (p & 1) * 4096;
        int sw = row & 7;
#pragma unroll
        for (int es = 0; es < 4; es++) {
            int ph = (4 * es + kg) ^ sw;
            s16x8 bb = *(const s16x8*)(L + row * 256 + ph * 16);
            acc[0][p] = MFMA16(afr[0][es], bb, acc[0][p]);
            acc[1][p] = MFMA16(afr[1][es], bb, acc[1][p]);
        }
        if (p <= 5) {
            LGKMCNT0();
            SCHEDBAR();
            STAGE_D(wb + (p & 1) * 4096, p + 2) FENCE();
        }
        // bias + tanh + mask
#pragma unroll
        for (int s = 0; s < 2; s++)
#pragma unroll
            for (int r = 0; r < 4; r++) {
                acc[s][p][r] = 10.f * fast_tanh(fmaf(acc[s][p][r], invs, -a2ls * cdv[s][r]))
                             + nfv[s][r];
            }
    }

    // ===== softmax over m (in-lane p, row-lanes, then 4 wave quarters) =====
    __syncthreads();   // D buffers dead; redm/reds region (aliased) now safe
    float mx[2][4], sm[2][4];
#pragma unroll
    for (int s = 0; s < 2; s++)
#pragma unroll
        for (int r = 0; r < 4; r++) {
            float m = acc[s][0][r];
#pragma unroll
            for (int p = 1; p < 8; p++) m = fmaxf(m, acc[s][p][r]);
#pragma unroll
            for (int sh = 1; sh < 16; sh <<= 1) m = fmaxf(m, __shfl_xor(m, sh, 64));
            mx[s][r] = m;
        }
    if (row == 0) {
#pragma unroll
        for (int s = 0; s < 2; s++)
#pragma unroll
            for (int r = 0; r < 4; r++) redm[(s * 16 + kg * 4 + r) * 4 + w] = mx[s][r];
    }
    __syncthreads();
#pragma unroll
    for (int s = 0; s < 2; s++)
#pragma unroll
        for (int r = 0; r < 4; r++) {
            int nl = s * 16 + kg * 4 + r;
            float m = fmaxf(fmaxf(redm[nl * 4 + 0], redm[nl * 4 + 1]),
                            fmaxf(redm[nl * 4 + 2], redm[nl * 4 + 3]));
            float sum = 0.f;
#pragma unroll
            for (int p = 0; p < 8; p++) {
                float e = __expf(acc[s][p][r] - m);
                acc[s][p][r] = e;
                sum += e;
            }
#pragma unroll
            for (int sh = 1; sh < 16; sh <<= 1) sum += __shfl_xor(sum, sh, 64);
            sm[s][r] = sum;
        }
    if (row == 0) {
#pragma unroll
        for (int s = 0; s < 2; s++)
#pragma unroll
            for (int r = 0; r < 4; r++) reds[(s * 16 + kg * 4 + r) * 4 + w] = sm[s][r];
    }
    __syncthreads();
#pragma unroll
    for (int s = 0; s < 2; s++)
#pragma unroll
        for (int r = 0; r < 4; r++) {
            int nl = s * 16 + kg * 4 + r;
            float inv = 1.f / (reds[nl * 4 + 0] + reds[nl * 4 + 1]
                             + reds[nl * 4 + 2] + reds[nl * 4 + 3]);
            size_t ro = ((size_t)b * N + n0 + nl) * M + (size_t)w * 128 + row;
#pragma unroll
            for (int p = 0; p < 8; p++) {
                out[ro + p * 16] = acc[s][p][r] * inv;
            }
        }
}

extern "C" void kernel_launch(void* const* d_in, const int* in_sizes, int n_in,
                              void* d_out, int out_size, void* d_ws, size_t ws_size,
                              hipStream_t stream) {
    const float* encl  = (const float*)d_in[0];
    const float* loadv = (const float*)d_in[1];
    const float* cdist = (const float*)d_in[2];
    const float* ls    = (const float*)d_in[3];
    const float* ninf  = (const float*)d_in[4];
    const float* enc   = (const float*)d_in[5];
    const float* Wq    = (const float*)d_in[6];
    const float* Wk    = (const float*)d_in[7];
    const float* Wv    = (const float*)d_in[8];
    const float* a1    = (const float*)d_in[9];
    const float* a2    = (const float*)d_in[10];
    char* ws = (char*)d_ws;
    unsigned short* EKb     = (unsigned short*)(ws);                    // 16.8 MB
    unsigned short* EKVb    = (unsigned short*)(ws + 16777216);         // 16.8 MB
    unsigned short* Eb      = (unsigned short*)(ws + 33554432);         // 16.8 MB
    unsigned short* Wk_hi   = (unsigned short*)(ws + 50331648);
    unsigned short* Wk_lo   = (unsigned short*)(ws + 50331648 + 32768);
    unsigned short* Wv_hi   = (unsigned short*)(ws + 50331648 + 65536);
    unsigned short* Wv_lo   = (unsigned short*)(ws + 50331648 + 98304);
    unsigned short* Wq_hi   = (unsigned short*)(ws + 50331648 + 131072);
    unsigned short* Wq_lo   = (unsigned short*)(ws + 50331648 + 163840);
    float* out = (float*)d_out;

    k_prep_w<<<192, 256, 0, stream>>>(Wk, Wv, Wq, Wk_hi, Wk_lo, Wv_hi, Wv_lo, Wq_hi, Wq_lo);
    k_kv<<<dim3(8, 128), 256, 0, stream>>>(enc, Wk_hi, Wk_lo, Wv_hi, Wv_lo, EKb, EKVb);
    k_encpack<<<4096, 256, 0, stream>>>(enc, Eb);
    k_fused<<<2048, 256, 0, stream>>>(encl, loadv, Wq, Wq_hi, Wq_lo,
                                      cdist, ninf, EKVb, EKb, Eb,
                                      a1, a2, ls, out);
}

// Round 15
// 333.734 us; speedup vs baseline: 2.2668x; 1.1792x over previous
//
#include <hip/hip_runtime.h>
#include <math.h>

#define B 128
#define N 512
#define M 512
#define D 128

typedef __attribute__((ext_vector_type(8))) short s16x8;
typedef __attribute__((ext_vector_type(4))) short s16x4;
typedef __attribute__((ext_vector_type(4))) float f32x4;

#define MFMA16(a, b, c) __builtin_amdgcn_mfma_f32_16x16x32_bf16(a, b, c, 0, 0, 0)

#define FENCE()   asm volatile("" ::: "memory")
#define VMCNT4()  asm volatile("s_waitcnt vmcnt(4)" ::: "memory")
#define VMCNT8()  asm volatile("s_waitcnt vmcnt(8)" ::: "memory")
#define VMCNT12() asm volatile("s_waitcnt vmcnt(12)" ::: "memory")
#define VMCNT16() asm volatile("s_waitcnt vmcnt(16)" ::: "memory")
#define VMCNT20() asm volatile("s_waitcnt vmcnt(20)" ::: "memory")
#define LGKMCNT0() asm volatile("s_waitcnt lgkmcnt(0)" ::: "memory")
#define SCHEDBAR() __builtin_amdgcn_sched_barrier(0)

__device__ __forceinline__ void gload16(const void* g, void* l) {
    __builtin_amdgcn_global_load_lds(
        (const __attribute__((address_space(1))) unsigned int*)g,
        (__attribute__((address_space(3))) unsigned int*)l, 16, 0, 0);
}

__device__ __forceinline__ float fast_tanh(float x) {
    x = fminf(fmaxf(x, -15.f), 15.f);
    float E = __expf(2.f * x);
    return 1.f - 2.f / (E + 1.f);
}

__device__ __forceinline__ unsigned short bf16rne(float x) {
    unsigned u = __float_as_uint(x);
    return (unsigned short)((u + 0x7FFF + ((u >> 16) & 1)) >> 16);
}

__device__ __forceinline__ void fsplit(float x, short& h, short& l) {
    unsigned u = __float_as_uint(x);
    h = (short)(u >> 16);
    float fh = __uint_as_float(u & 0xffff0000u);
    l = (short)(__float_as_uint(x - fh) >> 16);
}

__device__ __forceinline__ void fsplit8(float4 x0, float4 x1, s16x8& h, s16x8& l) {
    short a, b;
    fsplit(x0.x, a, b); h[0] = a; l[0] = b;
    fsplit(x0.y, a, b); h[1] = a; l[1] = b;
    fsplit(x0.z, a, b); h[2] = a; l[2] = b;
    fsplit(x0.w, a, b); h[3] = a; l[3] = b;
    fsplit(x1.x, a, b); h[4] = a; l[4] = b;
    fsplit(x1.y, a, b); h[5] = a; l[5] = b;
    fsplit(x1.z, a, b); h[6] = a; l[6] = b;
    fsplit(x1.w, a, b); h[7] = a; l[7] = b;
}

// EB = exp(-a1ls*cd + ninf) -> single bf16 RNE
__device__ __forceinline__ void ebpack(float4 c0, float4 c1, float4 f0, float4 f1,
                                       float a1ls, s16x8& a) {
    a[0] = (short)bf16rne(__expf(fmaf(-a1ls, c0.x, f0.x)));
    a[1] = (short)bf16rne(__expf(fmaf(-a1ls, c0.y, f0.y)));
    a[2] = (short)bf16rne(__expf(fmaf(-a1ls, c0.z, f0.z)));
    a[3] = (short)bf16rne(__expf(fmaf(-a1ls, c0.w, f0.w)));
    a[4] = (short)bf16rne(__expf(fmaf(-a1ls, c1.x, f1.x)));
    a[5] = (short)bf16rne(__expf(fmaf(-a1ls, c1.y, f1.y)));
    a[6] = (short)bf16rne(__expf(fmaf(-a1ls, c1.z, f1.z)));
    a[7] = (short)bf16rne(__expf(fmaf(-a1ls, c1.w, f1.w)));
}

__global__ void k_prep_w(const float* __restrict__ Wk, const float* __restrict__ Wv,
                         const float* __restrict__ Wq,
                         unsigned short* __restrict__ Wk_hi, unsigned short* __restrict__ Wk_lo,
                         unsigned short* __restrict__ Wv_hi, unsigned short* __restrict__ Wv_lo,
                         unsigned short* __restrict__ Wq_hi, unsigned short* __restrict__ Wq_lo) {
    int i = blockIdx.x * 256 + threadIdx.x;  // 0..49151
    short h, l;
    if (i < 16384) {
        fsplit(Wk[i], h, l); Wk_hi[i] = (unsigned short)h; Wk_lo[i] = (unsigned short)l;
    } else if (i < 32768) {
        int j = i - 16384;
        fsplit(Wv[j], h, l); Wv_hi[j] = (unsigned short)h; Wv_lo[j] = (unsigned short)l;
    } else {
        int j = i - 32768; int e = j >> 7, d = j & 127;
        fsplit(Wq[e * 129 + d], h, l); Wq_hi[j] = (unsigned short)h; Wq_lo[j] = (unsigned short)l;
    }
}

// k = enc@Wk^T, v = enc@Wv^T; store bf16-RNE EK, EK*V as [b][e][m],
// SWIZZLED: within each 32-m group, 8-m chunk c stored at c ^ (e&3).
__global__ __launch_bounds__(256) void k_kv(const float* __restrict__ enc,
        const unsigned short* __restrict__ Wk_hi, const unsigned short* __restrict__ Wk_lo,
        const unsigned short* __restrict__ Wv_hi, const unsigned short* __restrict__ Wv_lo,
        unsigned short* __restrict__ EKb, unsigned short* __restrict__ EKVb) {
    int b = blockIdx.y;
    int wave = threadIdx.x >> 6, lane = threadIdx.x & 63;
    int row = lane & 15, kg = lane >> 4;
    int m0 = blockIdx.x * 64 + wave * 16;
    f32x4 acc[16];
#pragma unroll
    for (int i = 0; i < 16; i++) acc[i] = (f32x4)0.f;
    const float* ap = enc + ((size_t)b * M + m0 + row) * D + kg * 8;
#pragma unroll
    for (int ks = 0; ks < 4; ks++) {
        float4 x0 = *(const float4*)(ap + ks * 32);
        float4 x1 = *(const float4*)(ap + ks * 32 + 4);
        s16x8 ah, al;
        fsplit8(x0, x1, ah, al);
        int wb = ks * 32 + kg * 8;
#pragma unroll
        for (int ct = 0; ct < 8; ct++) {
            int e = ct * 16 + row;
            s16x8 bh = *(const s16x8*)(Wk_hi + e * D + wb);
            s16x8 bl = *(const s16x8*)(Wk_lo + e * D + wb);
            acc[ct] = MFMA16(ah, bh, acc[ct]);
            acc[ct] = MFMA16(al, bh, acc[ct]);
            acc[ct] = MFMA16(ah, bl, acc[ct]);
            bh = *(const s16x8*)(Wv_hi + e * D + wb);
            bl = *(const s16x8*)(Wv_lo + e * D + wb);
            acc[8 + ct] = MFMA16(ah, bh, acc[8 + ct]);
            acc[8 + ct] = MFMA16(al, bh, acc[8 + ct]);
            acc[8 + ct] = MFMA16(ah, bl, acc[8 + ct]);
        }
    }
#pragma unroll
    for (int ct = 0; ct < 8; ct++) {
        int e = ct * 16 + row;
        s16x4 kb, vb;
#pragma unroll
        for (int r = 0; r < 4; r++) {
            float ek = __expf(acc[ct][r]);
            float ev = ek * acc[8 + ct][r];
            kb[r] = (short)bf16rne(ek);
            vb[r] = (short)bf16rne(ev);
        }
        int m = m0 + kg * 4;
        int chunk = (m & 31) >> 3;
        int p = chunk ^ (e & 3);
        size_t o = ((size_t)b * D + e) * M + (size_t)(m & ~31) + p * 8 + (m & 7);
        *(s16x4*)(EKb + o) = kb;
        *(s16x4*)(EKVb + o) = vb;
    }
}

// Pack enc -> single bf16-RNE [b][m][128e], SWIZZLED: 8-e chunk c at c ^ (m&7)
__global__ void k_encpack(const float* __restrict__ enc, unsigned short* __restrict__ Eb) {
    size_t i = (size_t)blockIdx.x * 256 + threadIdx.x;   // chunk id
    size_t bm = i >> 4;
    int c = (int)(i & 15);
    int m = (int)(bm & 511);
    int p = c ^ (m & 7);
    const float* src = enc + bm * 128 + c * 8;
    float4 x0 = *(const float4*)(src);
    float4 x1 = *(const float4*)(src + 4);
    s16x8 v;
    v[0] = (short)bf16rne(x0.x); v[1] = (short)bf16rne(x0.y);
    v[2] = (short)bf16rne(x0.z); v[3] = (short)bf16rne(x0.w);
    v[4] = (short)bf16rne(x1.x); v[5] = (short)bf16rne(x1.y);
    v[6] = (short)bf16rne(x1.z); v[7] = (short)bf16rne(x1.w);
    *(s16x8*)(Eb + bm * 128 + p * 8) = v;
}

// MEGA-FUSED, barrier-free main loops; wave-private staging; LDS exactly 32 KB.
// launch_bounds(256,3): arch-VGPR budget ~170 -> allocator lands ~84, NO spill
// (r13/r14 showed (256,4/5) halve the arch budget under the unified file -> spill).
__global__ __launch_bounds__(256, 3) void k_fused(
        const float* __restrict__ encl, const float* __restrict__ loadv,
        const float* __restrict__ Wq,
        const unsigned short* __restrict__ Wq_hi, const unsigned short* __restrict__ Wq_lo,
        const float* __restrict__ cd, const float* __restrict__ ninf,
        const unsigned short* __restrict__ EKVb, const unsigned short* __restrict__ EKb,
        const unsigned short* __restrict__ Eb,
        const float* __restrict__ a1p, const float* __restrict__ a2p,
        const float* __restrict__ lsp, float* __restrict__ out) {
    int o = blockIdx.x;
    int xcd = o & 7, j = o >> 3;       // j 0..255
    int b = ((j >> 4) << 3) + xcd;     // 16 b's per XCD
    int nb = j & 15;
    int n0 = nb * 32;
    int w = threadIdx.x >> 6, lane = threadIdx.x & 63;
    int row = lane & 15, kg = lane >> 4;
    __shared__ __align__(16) char lds[32768];   // wave-private: wave w owns [w*8K, +8K)
    float* redm = (float*)lds;                  // aliased; used only after D bufs die
    float* reds = (float*)(lds + 512);
    float a1ls = a1p[0] * lsp[0];
    float a2ls = a2p[0] * lsp[0];
    const float invs = 0.08838834764831845f;  // 1/sqrt(128)
    char* wb = lds + w * 8192;                // 2 bufs x 4 KB

    // ===== Phase A: q-pass; sq = sigmoid(q) in regs (e = w*32 + ct*16 + row) =====
    f32x4 sqa[2][2];
#pragma unroll
    for (int s = 0; s < 2; s++)
#pragma unroll
        for (int ct = 0; ct < 2; ct++) sqa[s][ct] = (f32x4)0.f;
#pragma unroll
    for (int s = 0; s < 2; s++) {
        const float* ap = encl + ((size_t)b * N + n0 + s * 16 + row) * D + kg * 8;
#pragma unroll
        for (int ks = 0; ks < 4; ks++) {
            float4 x0 = *(const float4*)(ap + ks * 32);
            float4 x1 = *(const float4*)(ap + ks * 32 + 4);
            s16x8 ah, al;
            fsplit8(x0, x1, ah, al);
            int wqo = ks * 32 + kg * 8;
#pragma unroll
            for (int ct = 0; ct < 2; ct++) {
                int e = w * 32 + ct * 16 + row;
                s16x8 bh = *(const s16x8*)(Wq_hi + e * D + wqo);
                s16x8 bl = *(const s16x8*)(Wq_lo + e * D + wqo);
                sqa[s][ct] = MFMA16(ah, bh, sqa[s][ct]);
                sqa[s][ct] = MFMA16(al, bh, sqa[s][ct]);
                sqa[s][ct] = MFMA16(ah, bl, sqa[s][ct]);
            }
        }
    }
    float sqv[2][2][4];
#pragma unroll
    for (int s = 0; s < 2; s++)
#pragma unroll
        for (int ct = 0; ct < 2; ct++) {
            int e = w * 32 + ct * 16 + row;
            float wcol = Wq[e * 129 + 128];
#pragma unroll
            for (int r = 0; r < 4; r++) {
                int n = n0 + s * 16 + kg * 4 + r;
                float q = sqa[s][ct][r] + loadv[(size_t)b * N + n] * wcol;
                sqv[s][ct][r] = 1.f / (1.f + __expf(-q));
            }
        }
    FENCE();   // pin all phase-A vmem before the B ledger starts

    // ===== Phase B: num/den, wave-private e-slice [w*32, w*32+32) =====
    f32x4 accN[2][2], accD[2][2];
#pragma unroll
    for (int s = 0; s < 2; s++)
#pragma unroll
        for (int i = 0; i < 2; i++) { accN[s][i] = (f32x4)0.f; accD[s][i] = (f32x4)0.f; }
    const char* gEKV = (const char*)EKVb + (size_t)b * D * M * 2;
    const char* gEK  = (const char*)EKb  + (size_t)b * D * M * 2;
    const float* cdp0 = cd + ((size_t)b * N + n0 + row) * M + kg * 8;
    const float* nfp0 = ninf + ((size_t)b * N + n0 + row) * M + kg * 8;
    const float* cdp1 = cdp0 + (size_t)16 * M;
    const float* nfp1 = nfp0 + (size_t)16 * M;

// stage wave's 4 KB slice of tile mt into bufptr: [2 arr][32 e][64 B]
#define STAGE_B(bufptr, mt)                                                      \
    _Pragma("unroll")                                                            \
    for (int jv = 0; jv < 4; jv++) {                                             \
        int arr = jv >> 1;                                                       \
        int rem = (jv & 1) * 64 + lane;                                          \
        const char* gb = arr ? gEK : gEKV;                                       \
        gload16(gb + (size_t)(w * 32 + (rem >> 2)) * 1024 + (size_t)(mt) * 64 +  \
                    (rem & 3) * 16,                                              \
                (char*)(bufptr) + arr * 2048 + rem * 16);                        \
    }

    float4 Ac[2][2][2], Af[2][2][2];   // [parity][n-set][half]
#define LOAD_A(p, mt)                                                            \
    Ac[p][0][0] = *(const float4*)(cdp0 + (mt) * 32);                            \
    Ac[p][0][1] = *(const float4*)(cdp0 + (mt) * 32 + 4);                        \
    Af[p][0][0] = *(const float4*)(nfp0 + (mt) * 32);                            \
    Af[p][0][1] = *(const float4*)(nfp0 + (mt) * 32 + 4);                        \
    Ac[p][1][0] = *(const float4*)(cdp1 + (mt) * 32);                            \
    Ac[p][1][1] = *(const float4*)(cdp1 + (mt) * 32 + 4);                        \
    Af[p][1][0] = *(const float4*)(nfp1 + (mt) * 32);                            \
    Af[p][1][1] = *(const float4*)(nfp1 + (mt) * 32 + 4);

    // prologue order (fenced): A0, S0, A1, S1
    LOAD_A(0, 0) FENCE();
    STAGE_B(wb, 0) FENCE();
    LOAD_A(1, 1) FENCE();
    STAGE_B(wb + 4096, 1) FENCE();

    int rbB = row * 64 + ((kg ^ (row & 3)) << 4);
#pragma unroll
    for (int mt = 0; mt < 16; mt++) {
        // W(t): younger-than-S(t) = {t<2: 12 ; 2..14: A(t)8+S(t+1)4+A(t+1)8 = 20 ; 15: 8}
        if (mt < 2) { VMCNT12(); } else if (mt < 15) { VMCNT20(); } else { VMCNT8(); }
        SCHEDBAR();
        int p = mt & 1;
        s16x8 a0, a1;
        ebpack(Ac[p][0][0], Ac[p][0][1], Af[p][0][0], Af[p][0][1], a1ls, a0);
        ebpack(Ac[p][1][0], Ac[p][1][1], Af[p][1][0], Af[p][1][1], a1ls, a1);
        const char* L = wb + p * 4096;
#pragma unroll
        for (int ct = 0; ct < 2; ct++) {
            int ro = ct * 1024 + rbB;
            s16x8 bv = *(const s16x8*)(L + ro);           // EKV
            s16x8 bk = *(const s16x8*)(L + 2048 + ro);    // EK
            accN[0][ct] = MFMA16(a0, bv, accN[0][ct]);
            accN[1][ct] = MFMA16(a1, bv, accN[1][ct]);
            accD[0][ct] = MFMA16(a0, bk, accD[0][ct]);
            accD[1][ct] = MFMA16(a1, bk, accD[1][ct]);
        }
        if (mt <= 13) {
            LGKMCNT0();   // own ds_reads of this buffer done -> safe to restage
            SCHEDBAR();
            STAGE_B(wb + p * 4096, mt + 2) FENCE();
            LOAD_A(p, mt + 2) FENCE();
        }
    }

    // ===== Phase C: aafm = sq*nan_to_num(num/den), single bf16-RNE bounce =====
    __syncthreads();   // all waves done with B buffers
    unsigned short* af = (unsigned short*)lds;   // 8 KB: [32 n][128 e] bf16
#pragma unroll
    for (int s = 0; s < 2; s++)
#pragma unroll
        for (int ct = 0; ct < 2; ct++) {
            int e = w * 32 + ct * 16 + row;
#pragma unroll
            for (int r = 0; r < 4; r++) {
                int nl = s * 16 + kg * 4 + r;
                float num = accN[s][ct][r], den = accD[s][ct][r];
                float ww = (den != 0.f) ? num / den : 0.f;
                af[nl * 128 + e] = bf16rne(sqv[s][ct][r] * ww);
            }
        }
    __syncthreads();
    s16x8 afr[2][4];   // A-frags for score: [n-set][es]
#pragma unroll
    for (int s = 0; s < 2; s++)
#pragma unroll
        for (int es = 0; es < 4; es++)
            afr[s][es] = *(const s16x8*)(af + (s * 16 + row) * 128 + es * 32 + kg * 8);
    __syncthreads();   // af dead; lds reused by wave-private D staging
    FENCE();

    // ===== Phase D: score, wave-private m-quarter [w*128, w*128+128) =====
    // acc[s][p]: n = n0 + s*16 + kg*4 + r ; m = w*128 + p*16 + row
    f32x4 acc[2][8];
#pragma unroll
    for (int s = 0; s < 2; s++)
#pragma unroll
        for (int p = 0; p < 8; p++) acc[s][p] = (f32x4)0.f;
    const char* gEb = (const char*)Eb + (size_t)b * M * 256;

// stage wave's 4 KB (16 m x 256 B) of tile p into bufptr
#define STAGE_D(bufptr, p)                                                       \
    _Pragma("unroll")                                                            \
    for (int jv = 0; jv < 4; jv++) {                                             \
        int id = jv * 64 + lane;                                                 \
        gload16(gEb + (size_t)(w * 128 + (p) * 16 + (id >> 4)) * 256 + (id & 15) * 16, \
                (char*)(bufptr) + id * 16);                                      \
    }

    // prologue (fenced): S0, S1; A loads are depth-1 in-loop (cd/ninf L2-hot)
    STAGE_D(wb, 0) FENCE();
    STAGE_D(wb + 4096, 1) FENCE();

#pragma unroll
    for (int p = 0; p < 8; p++) {
        // W(p): younger-than-S(p) = {0: S1 = 4 ; 1..6: A(p-1)16 + S(p+1)4 = 20 ; 7: A(6) = 16}
        if (p == 0) { VMCNT4(); } else if (p < 7) { VMCNT20(); } else { VMCNT16(); }
        SCHEDBAR();
        // this phase's cd/ninf (L2-hot from phase B) — used after MFMA
        float cdv[2][4], nfv[2][4];
#pragma unroll
        for (int s = 0; s < 2; s++)
#pragma unroll
            for (int r = 0; r < 4; r++) {
                size_t idx = ((size_t)b * N + n0 + s * 16 + kg * 4 + r) * M
                           + (size_t)w * 128 + (size_t)p * 16 + row;
                cdv[s][r] = cd[idx];
                nfv[s][r] = ninf[idx];
            }
        FENCE();
        const char* L = wb + (p & 1) * 4096;
        int sw = row & 7;
#pragma unroll
        for (int es = 0; es < 4; es++) {
            int ph = (4 * es + kg) ^ sw;
            s16x8 bb = *(const s16x8*)(L + row * 256 + ph * 16);
            acc[0][p] = MFMA16(afr[0][es], bb, acc[0][p]);
            acc[1][p] = MFMA16(afr[1][es], bb, acc[1][p]);
        }
        if (p <= 5) {
            LGKMCNT0();
            SCHEDBAR();
            STAGE_D(wb + (p & 1) * 4096, p + 2) FENCE();
        }
        // bias + tanh + mask
#pragma unroll
        for (int s = 0; s < 2; s++)
#pragma unroll
            for (int r = 0; r < 4; r++) {
                acc[s][p][r] = 10.f * fast_tanh(fmaf(acc[s][p][r], invs, -a2ls * cdv[s][r]))
                             + nfv[s][r];
            }
    }

    // ===== softmax over m (in-lane p, row-lanes, then 4 wave quarters) =====
    __syncthreads();   // D buffers dead; redm/reds region (aliased) now safe
    float mx[2][4], sm[2][4];
#pragma unroll
    for (int s = 0; s < 2; s++)
#pragma unroll
        for (int r = 0; r < 4; r++) {
            float m = acc[s][0][r];
#pragma unroll
            for (int p = 1; p < 8; p++) m = fmaxf(m, acc[s][p][r]);
#pragma unroll
            for (int sh = 1; sh < 16; sh <<= 1) m = fmaxf(m, __shfl_xor(m, sh, 64));
            mx[s][r] = m;
        }
    if (row == 0) {
#pragma unroll
        for (int s = 0; s < 2; s++)
#pragma unroll
            for (int r = 0; r < 4; r++) redm[(s * 16 + kg * 4 + r) * 4 + w] = mx[s][r];
    }
    __syncthreads();
#pragma unroll
    for (int s = 0; s < 2; s++)
#pragma unroll
        for (int r = 0; r < 4; r++) {
            int nl = s * 16 + kg * 4 + r;
            float m = fmaxf(fmaxf(redm[nl * 4 + 0], redm[nl * 4 + 1]),
                            fmaxf(redm[nl * 4 + 2], redm[nl * 4 + 3]));
            float sum = 0.f;
#pragma unroll
            for (int p = 0; p < 8; p++) {
                float e = __expf(acc[s][p][r] - m);
                acc[s][p][r] = e;
                sum += e;
            }
#pragma unroll
            for (int sh = 1; sh < 16; sh <<= 1) sum += __shfl_xor(sum, sh, 64);
            sm[s][r] = sum;
        }
    if (row == 0) {
#pragma unroll
        for (int s = 0; s < 2; s++)
#pragma unroll
            for (int r = 0; r < 4; r++) reds[(s * 16 + kg * 4 + r) * 4 + w] = sm[s][r];
    }
    __syncthreads();
#pragma unroll
    for (int s = 0; s < 2; s++)
#pragma unroll
        for (int r = 0; r < 4; r++) {
            int nl = s * 16 + kg * 4 + r;
            float inv = 1.f / (reds[nl * 4 + 0] + reds[nl * 4 + 1]
                             + reds[nl * 4 + 2] + reds[nl * 4 + 3]);
            size_t ro = ((size_t)b * N + n0 + nl) * M + (size_t)w * 128 + row;
#pragma unroll
            for (int p = 0; p < 8; p++) {
                out[ro + p * 16] = acc[s][p][r] * inv;
            }
        }
}

extern "C" void kernel_launch(void* const* d_in, const int* in_sizes, int n_in,
                              void* d_out, int out_size, void* d_ws, size_t ws_size,
                              hipStream_t stream) {
    const float* encl  = (const float*)d_in[0];
    const float* loadv = (const float*)d_in[1];
    const float* cdist = (const float*)d_in[2];
    const float* ls    = (const float*)d_in[3];
    const float* ninf  = (const float*)d_in[4];
    const float* enc   = (const float*)d_in[5];
    const float* Wq    = (const float*)d_in[6];
    const float* Wk    = (const float*)d_in[7];
    const float* Wv    = (const float*)d_in[8];
    const float* a1    = (const float*)d_in[9];
    const float* a2    = (const float*)d_in[10];
    char* ws = (char*)d_ws;
    unsigned short* EKb     = (unsigned short*)(ws);                    // 16.8 MB
    unsigned short* EKVb    = (unsigned short*)(ws + 16777216);         // 16.8 MB
    unsigned short* Eb      = (unsigned short*)(ws + 33554432);         // 16.8 MB
    unsigned short* Wk_hi   = (unsigned short*)(ws + 50331648);
    unsigned short* Wk_lo   = (unsigned short*)(ws + 50331648 + 32768);
    unsigned short* Wv_hi   = (unsigned short*)(ws + 50331648 + 65536);
    unsigned short* Wv_lo   = (unsigned short*)(ws + 50331648 + 98304);
    unsigned short* Wq_hi   = (unsigned short*)(ws + 50331648 + 131072);
    unsigned short* Wq_lo   = (unsigned short*)(ws + 50331648 + 163840);
    float* out = (float*)d_out;

    k_prep_w<<<192, 256, 0, stream>>>(Wk, Wv, Wq, Wk_hi, Wk_lo, Wv_hi, Wv_lo, Wq_hi, Wq_lo);
    k_kv<<<dim3(8, 128), 256, 0, stream>>>(enc, Wk_hi, Wk_lo, Wv_hi, Wv_lo, EKb, EKVb);
    k_encpack<<<4096, 256, 0, stream>>>(enc, Eb);
    k_fused<<<2048, 256, 0, stream>>>(encl, loadv, Wq, Wq_hi, Wq_lo,
                                      cdist, ninf, EKVb, EKb, Eb,
                                      a1, a2, ls, out);
}

// Round 16
// 329.191 us; speedup vs baseline: 2.2980x; 1.0138x over previous
//
#include <hip/hip_runtime.h>
#include <math.h>

#define B 128
#define N 512
#define M 512
#define D 128

typedef __attribute__((ext_vector_type(8))) short s16x8;
typedef __attribute__((ext_vector_type(4))) short s16x4;
typedef __attribute__((ext_vector_type(4))) float f32x4;

#define MFMA16(a, b, c) __builtin_amdgcn_mfma_f32_16x16x32_bf16(a, b, c, 0, 0, 0)

__device__ __forceinline__ float fast_tanh(float x) {
    x = fminf(fmaxf(x, -15.f), 15.f);
    float E = __expf(2.f * x);
    return 1.f - 2.f / (E + 1.f);
}

__device__ __forceinline__ unsigned short bf16rne(float x) {
    unsigned u = __float_as_uint(x);
    return (unsigned short)((u + 0x7FFF + ((u >> 16) & 1)) >> 16);
}

__device__ __forceinline__ void fsplit(float x, short& h, short& l) {
    unsigned u = __float_as_uint(x);
    h = (short)(u >> 16);
    float fh = __uint_as_float(u & 0xffff0000u);
    l = (short)(__float_as_uint(x - fh) >> 16);
}

__device__ __forceinline__ void fsplit8(float4 x0, float4 x1, s16x8& h, s16x8& l) {
    short a, b;
    fsplit(x0.x, a, b); h[0] = a; l[0] = b;
    fsplit(x0.y, a, b); h[1] = a; l[1] = b;
    fsplit(x0.z, a, b); h[2] = a; l[2] = b;
    fsplit(x0.w, a, b); h[3] = a; l[3] = b;
    fsplit(x1.x, a, b); h[4] = a; l[4] = b;
    fsplit(x1.y, a, b); h[5] = a; l[5] = b;
    fsplit(x1.z, a, b); h[6] = a; l[6] = b;
    fsplit(x1.w, a, b); h[7] = a; l[7] = b;
}

// EB = exp(-a1ls*cd + ninf) -> single bf16 RNE
__device__ __forceinline__ void ebpack(float4 c0, float4 c1, float4 f0, float4 f1,
                                       float a1ls, s16x8& a) {
    a[0] = (short)bf16rne(__expf(fmaf(-a1ls, c0.x, f0.x)));
    a[1] = (short)bf16rne(__expf(fmaf(-a1ls, c0.y, f0.y)));
    a[2] = (short)bf16rne(__expf(fmaf(-a1ls, c0.z, f0.z)));
    a[3] = (short)bf16rne(__expf(fmaf(-a1ls, c0.w, f0.w)));
    a[4] = (short)bf16rne(__expf(fmaf(-a1ls, c1.x, f1.x)));
    a[5] = (short)bf16rne(__expf(fmaf(-a1ls, c1.y, f1.y)));
    a[6] = (short)bf16rne(__expf(fmaf(-a1ls, c1.z, f1.z)));
    a[7] = (short)bf16rne(__expf(fmaf(-a1ls, c1.w, f1.w)));
}

__global__ void k_prep_w(const float* __restrict__ Wk, const float* __restrict__ Wv,
                         const float* __restrict__ Wq,
                         unsigned short* __restrict__ Wk_hi, unsigned short* __restrict__ Wk_lo,
                         unsigned short* __restrict__ Wv_hi, unsigned short* __restrict__ Wv_lo,
                         unsigned short* __restrict__ Wq_hi, unsigned short* __restrict__ Wq_lo) {
    int i = blockIdx.x * 256 + threadIdx.x;  // 0..49151
    short h, l;
    if (i < 16384) {
        fsplit(Wk[i], h, l); Wk_hi[i] = (unsigned short)h; Wk_lo[i] = (unsigned short)l;
    } else if (i < 32768) {
        int j = i - 16384;
        fsplit(Wv[j], h, l); Wv_hi[j] = (unsigned short)h; Wv_lo[j] = (unsigned short)l;
    } else {
        int j = i - 32768; int e = j >> 7, d = j & 127;
        fsplit(Wq[e * 129 + d], h, l); Wq_hi[j] = (unsigned short)h; Wq_lo[j] = (unsigned short)l;
    }
}

// k = enc@Wk^T, v = enc@Wv^T; store bf16-RNE EK, EK*V as [b][e][m] (m-chunk c at
// c ^ (e&3) within 32-m group). ALSO emits Eb = bf16(enc) [b][m][e] (e-chunk c at
// c ^ (m&7)) -- fused former k_encpack.
__global__ __launch_bounds__(256) void k_kv(const float* __restrict__ enc,
        const unsigned short* __restrict__ Wk_hi, const unsigned short* __restrict__ Wk_lo,
        const unsigned short* __restrict__ Wv_hi, const unsigned short* __restrict__ Wv_lo,
        unsigned short* __restrict__ EKb, unsigned short* __restrict__ EKVb,
        unsigned short* __restrict__ Eb) {
    int b = blockIdx.y;
    int wave = threadIdx.x >> 6, lane = threadIdx.x & 63;
    int row = lane & 15, kg = lane >> 4;
    int m0 = blockIdx.x * 64 + wave * 16;
    f32x4 acc[16];
#pragma unroll
    for (int i = 0; i < 16; i++) acc[i] = (f32x4)0.f;
    const float* ap = enc + ((size_t)b * M + m0 + row) * D + kg * 8;
    int menc = m0 + row;
#pragma unroll
    for (int ks = 0; ks < 4; ks++) {
        float4 x0 = *(const float4*)(ap + ks * 32);
        float4 x1 = *(const float4*)(ap + ks * 32 + 4);
        s16x8 ah, al;
        fsplit8(x0, x1, ah, al);
        // fused encpack: this lane owns e-chunk c = ks*4 + kg of row menc
        s16x8 ev;
        ev[0] = (short)bf16rne(x0.x); ev[1] = (short)bf16rne(x0.y);
        ev[2] = (short)bf16rne(x0.z); ev[3] = (short)bf16rne(x0.w);
        ev[4] = (short)bf16rne(x1.x); ev[5] = (short)bf16rne(x1.y);
        ev[6] = (short)bf16rne(x1.z); ev[7] = (short)bf16rne(x1.w);
        int c = ks * 4 + kg;
        *(s16x8*)(Eb + ((size_t)b * M + menc) * D + (size_t)((c ^ (menc & 7)) * 8)) = ev;
        int wb = ks * 32 + kg * 8;
#pragma unroll
        for (int ct = 0; ct < 8; ct++) {
            int e = ct * 16 + row;
            s16x8 bh = *(const s16x8*)(Wk_hi + e * D + wb);
            s16x8 bl = *(const s16x8*)(Wk_lo + e * D + wb);
            acc[ct] = MFMA16(ah, bh, acc[ct]);
            acc[ct] = MFMA16(al, bh, acc[ct]);
            acc[ct] = MFMA16(ah, bl, acc[ct]);
            bh = *(const s16x8*)(Wv_hi + e * D + wb);
            bl = *(const s16x8*)(Wv_lo + e * D + wb);
            acc[8 + ct] = MFMA16(ah, bh, acc[8 + ct]);
            acc[8 + ct] = MFMA16(al, bh, acc[8 + ct]);
            acc[8 + ct] = MFMA16(ah, bl, acc[8 + ct]);
        }
    }
#pragma unroll
    for (int ct = 0; ct < 8; ct++) {
        int e = ct * 16 + row;
        s16x4 kb, vb;
#pragma unroll
        for (int r = 0; r < 4; r++) {
            float ek = __expf(acc[ct][r]);
            float ev = ek * acc[8 + ct][r];
            kb[r] = (short)bf16rne(ek);
            vb[r] = (short)bf16rne(ev);
        }
        int m = m0 + kg * 4;
        int chunk = (m & 31) >> 3;
        int p = chunk ^ (e & 3);
        size_t o = ((size_t)b * D + e) * M + (size_t)(m & ~31) + p * 8 + (m & 7);
        *(s16x4*)(EKb + o) = kb;
        *(s16x4*)(EKVb + o) = vb;
    }
}

// MEGA-FUSED: q + numden + aafm + score + softmax. NO LDS staging in main loops:
// B-operands (L2-hot: 16 same-b blocks per XCD) loaded directly into parity-rotated
// register buffers 2 tiles ahead; cd/ninf 1 tile ahead; compiler-managed waitcnt.
// LDS = 9.2 KB (aafm bounce + reductions) only.
__global__ __launch_bounds__(256, 3) void k_fused(
        const float* __restrict__ encl, const float* __restrict__ loadv,
        const float* __restrict__ Wq,
        const unsigned short* __restrict__ Wq_hi, const unsigned short* __restrict__ Wq_lo,
        const float* __restrict__ cd, const float* __restrict__ ninf,
        const unsigned short* __restrict__ EKVb, const unsigned short* __restrict__ EKb,
        const unsigned short* __restrict__ Eb,
        const float* __restrict__ a1p, const float* __restrict__ a2p,
        const float* __restrict__ lsp, float* __restrict__ out) {
    int o = blockIdx.x;
    int xcd = o & 7, j = o >> 3;       // j 0..255
    int b = ((j >> 4) << 3) + xcd;     // 16 b's per XCD, nb-major (same-b co-resident)
    int nb = j & 15;
    int n0 = nb * 32;
    int w = threadIdx.x >> 6, lane = threadIdx.x & 63;
    int row = lane & 15, kg = lane >> 4;
    __shared__ __align__(16) unsigned short af[32 * 128];   // 8 KB aafm bounce
    __shared__ float redm[32][4], reds[32][4];               // 1 KB reductions
    float a1ls = a1p[0] * lsp[0];
    float a2ls = a2p[0] * lsp[0];
    const float invs = 0.08838834764831845f;  // 1/sqrt(128)

    // ===== Phase A: q-pass; sq = sigmoid(q) in regs (e = w*32 + ct*16 + row) =====
    f32x4 sqa[2][2];
#pragma unroll
    for (int s = 0; s < 2; s++)
#pragma unroll
        for (int ct = 0; ct < 2; ct++) sqa[s][ct] = (f32x4)0.f;
#pragma unroll
    for (int s = 0; s < 2; s++) {
        const float* ap = encl + ((size_t)b * N + n0 + s * 16 + row) * D + kg * 8;
#pragma unroll
        for (int ks = 0; ks < 4; ks++) {
            float4 x0 = *(const float4*)(ap + ks * 32);
            float4 x1 = *(const float4*)(ap + ks * 32 + 4);
            s16x8 ah, al;
            fsplit8(x0, x1, ah, al);
            int wqo = ks * 32 + kg * 8;
#pragma unroll
            for (int ct = 0; ct < 2; ct++) {
                int e = w * 32 + ct * 16 + row;
                s16x8 bh = *(const s16x8*)(Wq_hi + e * D + wqo);
                s16x8 bl = *(const s16x8*)(Wq_lo + e * D + wqo);
                sqa[s][ct] = MFMA16(ah, bh, sqa[s][ct]);
                sqa[s][ct] = MFMA16(al, bh, sqa[s][ct]);
                sqa[s][ct] = MFMA16(ah, bl, sqa[s][ct]);
            }
        }
    }
    float sqv[2][2][4];
#pragma unroll
    for (int s = 0; s < 2; s++)
#pragma unroll
        for (int ct = 0; ct < 2; ct++) {
            int e = w * 32 + ct * 16 + row;
            float wcol = Wq[e * 129 + 128];
#pragma unroll
            for (int r = 0; r < 4; r++) {
                int n = n0 + s * 16 + kg * 4 + r;
                float q = sqa[s][ct][r] + loadv[(size_t)b * N + n] * wcol;
                sqv[s][ct][r] = 1.f / (1.f + __expf(-q));
            }
        }

    // ===== Phase B: num/den; wave-private e-slice [w*32, +32); direct B loads =====
    f32x4 accN[2][2], accD[2][2];
#pragma unroll
    for (int s = 0; s < 2; s++)
#pragma unroll
        for (int i = 0; i < 2; i++) { accN[s][i] = (f32x4)0.f; accD[s][i] = (f32x4)0.f; }
    const float* cdp0 = cd + ((size_t)b * N + n0 + row) * M + kg * 8;
    const float* nfp0 = ninf + ((size_t)b * N + n0 + row) * M + kg * 8;
    const float* cdp1 = cdp0 + (size_t)16 * M;
    const float* nfp1 = nfp0 + (size_t)16 * M;
    // per-lane B base pointers: e = w*32 + ct*16 + row; swizzled chunk (kg^(row&3))
    int swo = (kg ^ (row & 3)) << 4;   // bytes
    const char* bV[2]; const char* bK[2];
#pragma unroll
    for (int ct = 0; ct < 2; ct++) {
        int e = w * 32 + ct * 16 + row;
        bV[ct] = (const char*)EKVb + (((size_t)b * D + e) * M) * 2 + swo;
        bK[ct] = (const char*)EKb  + (((size_t)b * D + e) * M) * 2 + swo;
    }
    float4 Ac[2][2][2], Af[2][2][2];   // [parity][n-set][half]
    s16x8 BV[2][2], BK[2][2];          // [parity][ct]
#define LOAD_A(p, mt)                                                            \
    Ac[p][0][0] = *(const float4*)(cdp0 + (mt) * 32);                            \
    Ac[p][0][1] = *(const float4*)(cdp0 + (mt) * 32 + 4);                        \
    Af[p][0][0] = *(const float4*)(nfp0 + (mt) * 32);                            \
    Af[p][0][1] = *(const float4*)(nfp0 + (mt) * 32 + 4);                        \
    Ac[p][1][0] = *(const float4*)(cdp1 + (mt) * 32);                            \
    Ac[p][1][1] = *(const float4*)(cdp1 + (mt) * 32 + 4);                        \
    Af[p][1][0] = *(const float4*)(nfp1 + (mt) * 32);                            \
    Af[p][1][1] = *(const float4*)(nfp1 + (mt) * 32 + 4);
#define LOAD_B(p, mt)                                                            \
    BV[p][0] = *(const s16x8*)(bV[0] + (mt) * 64);                               \
    BV[p][1] = *(const s16x8*)(bV[1] + (mt) * 64);                               \
    BK[p][0] = *(const s16x8*)(bK[0] + (mt) * 64);                               \
    BK[p][1] = *(const s16x8*)(bK[1] + (mt) * 64);

    LOAD_A(0, 0) LOAD_B(0, 0)
    LOAD_A(1, 1) LOAD_B(1, 1)

#pragma unroll
    for (int mt = 0; mt < 16; mt++) {
        int p = mt & 1;
        s16x8 a0, a1;
        ebpack(Ac[p][0][0], Ac[p][0][1], Af[p][0][0], Af[p][0][1], a1ls, a0);
        ebpack(Ac[p][1][0], Ac[p][1][1], Af[p][1][0], Af[p][1][1], a1ls, a1);
#pragma unroll
        for (int ct = 0; ct < 2; ct++) {
            accN[0][ct] = MFMA16(a0, BV[p][ct], accN[0][ct]);
            accN[1][ct] = MFMA16(a1, BV[p][ct], accN[1][ct]);
            accD[0][ct] = MFMA16(a0, BK[p][ct], accD[0][ct]);
            accD[1][ct] = MFMA16(a1, BK[p][ct], accD[1][ct]);
        }
        if (mt <= 13) {
            LOAD_A(p, mt + 2)
            LOAD_B(p, mt + 2)
        }
    }

    // ===== Phase C: aafm = sq*nan_to_num(num/den), bf16 bounce via LDS =====
#pragma unroll
    for (int s = 0; s < 2; s++)
#pragma unroll
        for (int ct = 0; ct < 2; ct++) {
            int e = w * 32 + ct * 16 + row;
#pragma unroll
            for (int r = 0; r < 4; r++) {
                int nl = s * 16 + kg * 4 + r;
                float num = accN[s][ct][r], den = accD[s][ct][r];
                float ww = (den != 0.f) ? num / den : 0.f;
                af[nl * 128 + e] = bf16rne(sqv[s][ct][r] * ww);
            }
        }
    __syncthreads();
    s16x8 afr[2][4];   // A-frags for score: [n-set][es]
#pragma unroll
    for (int s = 0; s < 2; s++)
#pragma unroll
        for (int es = 0; es < 4; es++)
            afr[s][es] = *(const s16x8*)(af + (s * 16 + row) * 128 + es * 32 + kg * 8);

    // ===== Phase D: score; wave-private m-quarter [w*128, +128); direct Eb loads =====
    // acc[s][p]: n = n0 + s*16 + kg*4 + r ; m = w*128 + p*16 + row
    f32x4 acc[2][8];
#pragma unroll
    for (int s = 0; s < 2; s++)
#pragma unroll
        for (int p = 0; p < 8; p++) acc[s][p] = (f32x4)0.f;
    int dsw = row & 7;
    const char* bE = (const char*)Eb + ((size_t)b * M + w * 128 + row) * 256;
    const float* cdD0 = cd + ((size_t)b * N + n0 + kg * 4) * M + w * 128 + row;
    const float* nfD0 = ninf + ((size_t)b * N + n0 + kg * 4) * M + w * 128 + row;
    const float* cdD1 = cdD0 + (size_t)16 * M;
    const float* nfD1 = nfD0 + (size_t)16 * M;
    s16x8 EF[2][4];                    // [parity][es]
    float cdv[2][2][4], nfv[2][2][4];  // [slot][s][r]
#define LOAD_E(p, pt)                                                            \
    EF[p][0] = *(const s16x8*)(bE + (size_t)(pt) * 4096 + ((0 + kg) ^ dsw) * 16);  \
    EF[p][1] = *(const s16x8*)(bE + (size_t)(pt) * 4096 + ((4 + kg) ^ dsw) * 16);  \
    EF[p][2] = *(const s16x8*)(bE + (size_t)(pt) * 4096 + ((8 + kg) ^ dsw) * 16);  \
    EF[p][3] = *(const s16x8*)(bE + (size_t)(pt) * 4096 + ((12 + kg) ^ dsw) * 16);
#define LOAD_CDNF(sl, pt)                                                        \
    _Pragma("unroll")                                                            \
    for (int r = 0; r < 4; r++) {                                                \
        cdv[sl][0][r] = cdD0[(size_t)r * M + (pt) * 16];                         \
        nfv[sl][0][r] = nfD0[(size_t)r * M + (pt) * 16];                         \
        cdv[sl][1][r] = cdD1[(size_t)r * M + (pt) * 16];                         \
        nfv[sl][1][r] = nfD1[(size_t)r * M + (pt) * 16];                         \
    }

    LOAD_E(0, 0) LOAD_E(1, 1)
    LOAD_CDNF(0, 0)

#pragma unroll
    for (int p = 0; p < 8; p++) {
        int par = p & 1;
#pragma unroll
        for (int es = 0; es < 4; es++) {
            acc[0][p] = MFMA16(afr[0][es], EF[par][es], acc[0][p]);
            acc[1][p] = MFMA16(afr[1][es], EF[par][es], acc[1][p]);
        }
        if (p <= 5) { LOAD_E(par, p + 2) }
        if (p <= 6) { LOAD_CDNF(par ^ 1, p + 1) }
        // bias + tanh + mask with this tile's cd/ninf
#pragma unroll
        for (int s = 0; s < 2; s++)
#pragma unroll
            for (int r = 0; r < 4; r++) {
                acc[s][p][r] = 10.f * fast_tanh(fmaf(acc[s][p][r], invs, -a2ls * cdv[par][s][r]))
                             + nfv[par][s][r];
            }
    }

    // ===== softmax over m (in-lane p, row-lanes, then 4 wave quarters) =====
    float mx[2][4], sm[2][4];
#pragma unroll
    for (int s = 0; s < 2; s++)
#pragma unroll
        for (int r = 0; r < 4; r++) {
            float m = acc[s][0][r];
#pragma unroll
            for (int p = 1; p < 8; p++) m = fmaxf(m, acc[s][p][r]);
#pragma unroll
            for (int sh = 1; sh < 16; sh <<= 1) m = fmaxf(m, __shfl_xor(m, sh, 64));
            mx[s][r] = m;
        }
    if (row == 0) {
#pragma unroll
        for (int s = 0; s < 2; s++)
#pragma unroll
            for (int r = 0; r < 4; r++) redm[s * 16 + kg * 4 + r][w] = mx[s][r];
    }
    __syncthreads();
#pragma unroll
    for (int s = 0; s < 2; s++)
#pragma unroll
        for (int r = 0; r < 4; r++) {
            int nl = s * 16 + kg * 4 + r;
            float m = fmaxf(fmaxf(redm[nl][0], redm[nl][1]),
                            fmaxf(redm[nl][2], redm[nl][3]));
            float sum = 0.f;
#pragma unroll
            for (int p = 0; p < 8; p++) {
                float e = __expf(acc[s][p][r] - m);
                acc[s][p][r] = e;
                sum += e;
            }
#pragma unroll
            for (int sh = 1; sh < 16; sh <<= 1) sum += __shfl_xor(sum, sh, 64);
            sm[s][r] = sum;
        }
    if (row == 0) {
#pragma unroll
        for (int s = 0; s < 2; s++)
#pragma unroll
            for (int r = 0; r < 4; r++) reds[s * 16 + kg * 4 + r][w] = sm[s][r];
    }
    __syncthreads();
#pragma unroll
    for (int s = 0; s < 2; s++)
#pragma unroll
        for (int r = 0; r < 4; r++) {
            int nl = s * 16 + kg * 4 + r;
            float inv = 1.f / (reds[nl][0] + reds[nl][1] + reds[nl][2] + reds[nl][3]);
            size_t ro = ((size_t)b * N + n0 + nl) * M + (size_t)w * 128 + row;
#pragma unroll
            for (int p = 0; p < 8; p++) {
                out[ro + p * 16] = acc[s][p][r] * inv;
            }
        }
}

extern "C" void kernel_launch(void* const* d_in, const int* in_sizes, int n_in,
                              void* d_out, int out_size, void* d_ws, size_t ws_size,
                              hipStream_t stream) {
    const float* encl  = (const float*)d_in[0];
    const float* loadv = (const float*)d_in[1];
    const float* cdist = (const float*)d_in[2];
    const float* ls    = (const float*)d_in[3];
    const float* ninf  = (const float*)d_in[4];
    const float* enc   = (const float*)d_in[5];
    const float* Wq    = (const float*)d_in[6];
    const float* Wk    = (const float*)d_in[7];
    const float* Wv    = (const float*)d_in[8];
    const float* a1    = (const float*)d_in[9];
    const float* a2    = (const float*)d_in[10];
    char* ws = (char*)d_ws;
    unsigned short* EKb     = (unsigned short*)(ws);                    // 16.8 MB
    unsigned short* EKVb    = (unsigned short*)(ws + 16777216);         // 16.8 MB
    unsigned short* Eb      = (unsigned short*)(ws + 33554432);         // 16.8 MB
    unsigned short* Wk_hi   = (unsigned short*)(ws + 50331648);
    unsigned short* Wk_lo   = (unsigned short*)(ws + 50331648 + 32768);
    unsigned short* Wv_hi   = (unsigned short*)(ws + 50331648 + 65536);
    unsigned short* Wv_lo   = (unsigned short*)(ws + 50331648 + 98304);
    unsigned short* Wq_hi   = (unsigned short*)(ws + 50331648 + 131072);
    unsigned short* Wq_lo   = (unsigned short*)(ws + 50331648 + 163840);
    float* out = (float*)d_out;

    k_prep_w<<<192, 256, 0, stream>>>(Wk, Wv, Wq, Wk_hi, Wk_lo, Wv_hi, Wv_lo, Wq_hi, Wq_lo);
    k_kv<<<dim3(8, 128), 256, 0, stream>>>(enc, Wk_hi, Wk_lo, Wv_hi, Wv_lo, EKb, EKVb, Eb);
    k_fused<<<2048, 256, 0, stream>>>(encl, loadv, Wq, Wq_hi, Wq_lo,
                                      cdist, ninf, EKVb, EKb, Eb,
                                      a1, a2, ls, out);
}

// Round 17
// 326.039 us; speedup vs baseline: 2.3203x; 1.0097x over previous
//
#include <hip/hip_runtime.h>
#include <math.h>

#define B 128
#define N 512
#define M 512
#define D 128

typedef __attribute__((ext_vector_type(8))) short s16x8;
typedef __attribute__((ext_vector_type(4))) short s16x4;
typedef __attribute__((ext_vector_type(4))) float f32x4;

#define MFMA16(a, b, c) __builtin_amdgcn_mfma_f32_16x16x32_bf16(a, b, c, 0, 0, 0)

__device__ __forceinline__ float fast_tanh(float x) {
    x = fminf(fmaxf(x, -15.f), 15.f);
    float E = __expf(2.f * x);
    return 1.f - 2.f / (E + 1.f);
}

__device__ __forceinline__ unsigned short bf16rne(float x) {
    unsigned u = __float_as_uint(x);
    return (unsigned short)((u + 0x7FFF + ((u >> 16) & 1)) >> 16);
}

__device__ __forceinline__ void fsplit(float x, short& h, short& l) {
    unsigned u = __float_as_uint(x);
    h = (short)(u >> 16);
    float fh = __uint_as_float(u & 0xffff0000u);
    l = (short)(__float_as_uint(x - fh) >> 16);
}

__device__ __forceinline__ void fsplit8(float4 x0, float4 x1, s16x8& h, s16x8& l) {
    short a, b;
    fsplit(x0.x, a, b); h[0] = a; l[0] = b;
    fsplit(x0.y, a, b); h[1] = a; l[1] = b;
    fsplit(x0.z, a, b); h[2] = a; l[2] = b;
    fsplit(x0.w, a, b); h[3] = a; l[3] = b;
    fsplit(x1.x, a, b); h[4] = a; l[4] = b;
    fsplit(x1.y, a, b); h[5] = a; l[5] = b;
    fsplit(x1.z, a, b); h[6] = a; l[6] = b;
    fsplit(x1.w, a, b); h[7] = a; l[7] = b;
}

// EB = exp(-a1ls*cd + ninf) -> single bf16 RNE
__device__ __forceinline__ void ebpack(float4 c0, float4 c1, float4 f0, float4 f1,
                                       float a1ls, s16x8& a) {
    a[0] = (short)bf16rne(__expf(fmaf(-a1ls, c0.x, f0.x)));
    a[1] = (short)bf16rne(__expf(fmaf(-a1ls, c0.y, f0.y)));
    a[2] = (short)bf16rne(__expf(fmaf(-a1ls, c0.z, f0.z)));
    a[3] = (short)bf16rne(__expf(fmaf(-a1ls, c0.w, f0.w)));
    a[4] = (short)bf16rne(__expf(fmaf(-a1ls, c1.x, f1.x)));
    a[5] = (short)bf16rne(__expf(fmaf(-a1ls, c1.y, f1.y)));
    a[6] = (short)bf16rne(__expf(fmaf(-a1ls, c1.z, f1.z)));
    a[7] = (short)bf16rne(__expf(fmaf(-a1ls, c1.w, f1.w)));
}

__global__ void k_prep_w(const float* __restrict__ Wk, const float* __restrict__ Wv,
                         const float* __restrict__ Wq,
                         unsigned short* __restrict__ Wk_hi, unsigned short* __restrict__ Wk_lo,
                         unsigned short* __restrict__ Wv_hi, unsigned short* __restrict__ Wv_lo,
                         unsigned short* __restrict__ Wq_hi, unsigned short* __restrict__ Wq_lo) {
    int i = blockIdx.x * 256 + threadIdx.x;  // 0..49151
    short h, l;
    if (i < 16384) {
        fsplit(Wk[i], h, l); Wk_hi[i] = (unsigned short)h; Wk_lo[i] = (unsigned short)l;
    } else if (i < 32768) {
        int j = i - 16384;
        fsplit(Wv[j], h, l); Wv_hi[j] = (unsigned short)h; Wv_lo[j] = (unsigned short)l;
    } else {
        int j = i - 32768; int e = j >> 7, d = j & 127;
        fsplit(Wq[e * 129 + d], h, l); Wq_hi[j] = (unsigned short)h; Wq_lo[j] = (unsigned short)l;
    }
}

// k = enc@Wk^T, v = enc@Wv^T; store bf16-RNE EK, EK*V as [b][e][m] (m-chunk c at
// c ^ (e&3) within 32-m group). Also emits Eb = bf16(enc) [b][m][e] (e-chunk c at
// c ^ (m&7)).
__global__ __launch_bounds__(256) void k_kv(const float* __restrict__ enc,
        const unsigned short* __restrict__ Wk_hi, const unsigned short* __restrict__ Wk_lo,
        const unsigned short* __restrict__ Wv_hi, const unsigned short* __restrict__ Wv_lo,
        unsigned short* __restrict__ EKb, unsigned short* __restrict__ EKVb,
        unsigned short* __restrict__ Eb) {
    int b = blockIdx.y;
    int wave = threadIdx.x >> 6, lane = threadIdx.x & 63;
    int row = lane & 15, kg = lane >> 4;
    int m0 = blockIdx.x * 64 + wave * 16;
    f32x4 acc[16];
#pragma unroll
    for (int i = 0; i < 16; i++) acc[i] = (f32x4)0.f;
    const float* ap = enc + ((size_t)b * M + m0 + row) * D + kg * 8;
    int menc = m0 + row;
#pragma unroll
    for (int ks = 0; ks < 4; ks++) {
        float4 x0 = *(const float4*)(ap + ks * 32);
        float4 x1 = *(const float4*)(ap + ks * 32 + 4);
        s16x8 ah, al;
        fsplit8(x0, x1, ah, al);
        s16x8 ev;
        ev[0] = (short)bf16rne(x0.x); ev[1] = (short)bf16rne(x0.y);
        ev[2] = (short)bf16rne(x0.z); ev[3] = (short)bf16rne(x0.w);
        ev[4] = (short)bf16rne(x1.x); ev[5] = (short)bf16rne(x1.y);
        ev[6] = (short)bf16rne(x1.z); ev[7] = (short)bf16rne(x1.w);
        int c = ks * 4 + kg;
        *(s16x8*)(Eb + ((size_t)b * M + menc) * D + (size_t)((c ^ (menc & 7)) * 8)) = ev;
        int wb = ks * 32 + kg * 8;
#pragma unroll
        for (int ct = 0; ct < 8; ct++) {
            int e = ct * 16 + row;
            s16x8 bh = *(const s16x8*)(Wk_hi + e * D + wb);
            s16x8 bl = *(const s16x8*)(Wk_lo + e * D + wb);
            acc[ct] = MFMA16(ah, bh, acc[ct]);
            acc[ct] = MFMA16(al, bh, acc[ct]);
            acc[ct] = MFMA16(ah, bl, acc[ct]);
            bh = *(const s16x8*)(Wv_hi + e * D + wb);
            bl = *(const s16x8*)(Wv_lo + e * D + wb);
            acc[8 + ct] = MFMA16(ah, bh, acc[8 + ct]);
            acc[8 + ct] = MFMA16(al, bh, acc[8 + ct]);
            acc[8 + ct] = MFMA16(ah, bl, acc[8 + ct]);
        }
    }
#pragma unroll
    for (int ct = 0; ct < 8; ct++) {
        int e = ct * 16 + row;
        s16x4 kb, vb;
#pragma unroll
        for (int r = 0; r < 4; r++) {
            float ek = __expf(acc[ct][r]);
            float ev = ek * acc[8 + ct][r];
            kb[r] = (short)bf16rne(ek);
            vb[r] = (short)bf16rne(ev);
        }
        int m = m0 + kg * 4;
        int chunk = (m & 31) >> 3;
        int p = chunk ^ (e & 3);
        size_t o = ((size_t)b * D + e) * M + (size_t)(m & ~31) + p * 8 + (m & 7);
        *(s16x4*)(EKb + o) = kb;
        *(s16x4*)(EKVb + o) = vb;
    }
}

// MEGA-FUSED, register-lean: q + numden + aafm + score + softmax.
// Direct L2 loads, shallow buffers, A-frags for score re-read from LDS af.
__global__ __launch_bounds__(256, 3) void k_fused(
        const float* __restrict__ encl, const float* __restrict__ loadv,
        const float* __restrict__ Wq,
        const unsigned short* __restrict__ Wq_hi, const unsigned short* __restrict__ Wq_lo,
        const float* __restrict__ cd, const float* __restrict__ ninf,
        const unsigned short* __restrict__ EKVb, const unsigned short* __restrict__ EKb,
        const unsigned short* __restrict__ Eb,
        const float* __restrict__ a1p, const float* __restrict__ a2p,
        const float* __restrict__ lsp, float* __restrict__ out) {
    int o = blockIdx.x;
    int xcd = o & 7, j = o >> 3;       // j 0..255
    int b = ((j >> 4) << 3) + xcd;     // 16 b's per XCD (same-b co-resident)
    int nb = j & 15;
    int n0 = nb * 32;
    int w = threadIdx.x >> 6, lane = threadIdx.x & 63;
    int row = lane & 15, kg = lane >> 4;
    __shared__ __align__(16) char afb[32 * 272];   // aafm bounce, stride 272 B (17x16)
    __shared__ float redm[32][4], reds[32][4];
    float a1ls = a1p[0] * lsp[0];
    float a2ls = a2p[0] * lsp[0];
    const float invs = 0.08838834764831845f;  // 1/sqrt(128)

    // ===== Phase A: q-pass; sigmoid packed to bf16 pairs (8 regs) =====
    f32x4 sqa[2][2];
#pragma unroll
    for (int s = 0; s < 2; s++)
#pragma unroll
        for (int ct = 0; ct < 2; ct++) sqa[s][ct] = (f32x4)0.f;
#pragma unroll
    for (int s = 0; s < 2; s++) {
        const float* ap = encl + ((size_t)b * N + n0 + s * 16 + row) * D + kg * 8;
#pragma unroll
        for (int ks = 0; ks < 4; ks++) {
            float4 x0 = *(const float4*)(ap + ks * 32);
            float4 x1 = *(const float4*)(ap + ks * 32 + 4);
            s16x8 ah, al;
            fsplit8(x0, x1, ah, al);
            int wqo = ks * 32 + kg * 8;
#pragma unroll
            for (int ct = 0; ct < 2; ct++) {
                int e = w * 32 + ct * 16 + row;
                s16x8 bh = *(const s16x8*)(Wq_hi + e * D + wqo);
                s16x8 bl = *(const s16x8*)(Wq_lo + e * D + wqo);
                sqa[s][ct] = MFMA16(ah, bh, sqa[s][ct]);
                sqa[s][ct] = MFMA16(al, bh, sqa[s][ct]);
                sqa[s][ct] = MFMA16(ah, bl, sqa[s][ct]);
            }
        }
    }
    unsigned sqp[2][2][2];   // [s][ct][rpair]: 2 x bf16 sigmoid
#pragma unroll
    for (int s = 0; s < 2; s++)
#pragma unroll
        for (int ct = 0; ct < 2; ct++) {
            int e = w * 32 + ct * 16 + row;
            float wcol = Wq[e * 129 + 128];
#pragma unroll
            for (int rp = 0; rp < 2; rp++) {
                int n = n0 + s * 16 + kg * 4 + rp * 2;
                float q0 = sqa[s][ct][rp * 2] + loadv[(size_t)b * N + n] * wcol;
                float q1 = sqa[s][ct][rp * 2 + 1] + loadv[(size_t)b * N + n + 1] * wcol;
                unsigned lo = bf16rne(1.f / (1.f + __expf(-q0)));
                unsigned hi = bf16rne(1.f / (1.f + __expf(-q1)));
                sqp[s][ct][rp] = lo | (hi << 16);
            }
        }

    // ===== Phase B: num/den; single raw A slot + packed EA; B-operands depth-1 =====
    f32x4 accN[2][2], accD[2][2];
#pragma unroll
    for (int s = 0; s < 2; s++)
#pragma unroll
        for (int i = 0; i < 2; i++) { accN[s][i] = (f32x4)0.f; accD[s][i] = (f32x4)0.f; }
    const float* cdp0 = cd + ((size_t)b * N + n0 + row) * M + kg * 8;
    const float* nfp0 = ninf + ((size_t)b * N + n0 + row) * M + kg * 8;
    const float* cdp1 = cdp0 + (size_t)16 * M;
    const float* nfp1 = nfp0 + (size_t)16 * M;
    int swo = (kg ^ (row & 3)) << 4;   // bytes
    const char* bVp[2]; const char* bKp[2];
#pragma unroll
    for (int ct = 0; ct < 2; ct++) {
        int e = w * 32 + ct * 16 + row;
        bVp[ct] = (const char*)EKVb + (((size_t)b * D + e) * M) * 2 + swo;
        bKp[ct] = (const char*)EKb  + (((size_t)b * D + e) * M) * 2 + swo;
    }
    float4 Rc[2][2], Rf[2][2];   // single raw slot (tile in flight)
    s16x8 EA[2][2];              // packed A, parity x n-set
    s16x8 BV[2], BK[2];          // depth-1 B operands
#define RAWLOAD(mt)                                                              \
    Rc[0][0] = *(const float4*)(cdp0 + (mt) * 32);                               \
    Rc[0][1] = *(const float4*)(cdp0 + (mt) * 32 + 4);                           \
    Rf[0][0] = *(const float4*)(nfp0 + (mt) * 32);                               \
    Rf[0][1] = *(const float4*)(nfp0 + (mt) * 32 + 4);                           \
    Rc[1][0] = *(const float4*)(cdp1 + (mt) * 32);                               \
    Rc[1][1] = *(const float4*)(cdp1 + (mt) * 32 + 4);                           \
    Rf[1][0] = *(const float4*)(nfp1 + (mt) * 32);                               \
    Rf[1][1] = *(const float4*)(nfp1 + (mt) * 32 + 4);
#define EBCONV(p)                                                                \
    ebpack(Rc[0][0], Rc[0][1], Rf[0][0], Rf[0][1], a1ls, EA[p][0]);              \
    ebpack(Rc[1][0], Rc[1][1], Rf[1][0], Rf[1][1], a1ls, EA[p][1]);
#define LOADB(mt)                                                                \
    BV[0] = *(const s16x8*)(bVp[0] + (mt) * 64);                                 \
    BV[1] = *(const s16x8*)(bVp[1] + (mt) * 64);                                 \
    BK[0] = *(const s16x8*)(bKp[0] + (mt) * 64);                                 \
    BK[1] = *(const s16x8*)(bKp[1] + (mt) * 64);

    RAWLOAD(0)
    EBCONV(0)
    RAWLOAD(1)
    LOADB(0)

#pragma unroll
    for (int mt = 0; mt < 16; mt++) {
        int p = mt & 1;
#pragma unroll
        for (int ct = 0; ct < 2; ct++) {
            accN[0][ct] = MFMA16(EA[p][0], BV[ct], accN[0][ct]);
            accN[1][ct] = MFMA16(EA[p][1], BV[ct], accN[1][ct]);
            accD[0][ct] = MFMA16(EA[p][0], BK[ct], accD[0][ct]);
            accD[1][ct] = MFMA16(EA[p][1], BK[ct], accD[1][ct]);
        }
        if (mt <= 14) { EBCONV(p ^ 1) }      // converts tile mt+1 (raw loaded at mt-1)
        if (mt <= 13) { RAWLOAD(mt + 2) }    // WAR: after EBCONV consumed raw
        if (mt <= 14) { LOADB(mt + 1) }      // WAR: after this tile's MFMAs
    }

    // ===== Phase C: aafm = sq*nan_to_num(num/den) -> bf16 into LDS (stride 272 B) =====
#pragma unroll
    for (int s = 0; s < 2; s++)
#pragma unroll
        for (int ct = 0; ct < 2; ct++) {
            int e = w * 32 + ct * 16 + row;
#pragma unroll
            for (int r = 0; r < 4; r++) {
                int nl = s * 16 + kg * 4 + r;
                float num = accN[s][ct][r], den = accD[s][ct][r];
                float ww = (den != 0.f) ? num / den : 0.f;
                unsigned us = (r & 1) ? (sqp[s][ct][r >> 1] >> 16)
                                      : (sqp[s][ct][r >> 1] & 0xffffu);
                float sq = __uint_as_float(us << 16);
                *(unsigned short*)(afb + nl * 272 + e * 2) = bf16rne(sq * ww);
            }
        }
    __syncthreads();

    // ===== Phase D: score; A-frags re-read from afb; EF/cd/ninf single-slot =====
    f32x4 acc[2][8];
#pragma unroll
    for (int s = 0; s < 2; s++)
#pragma unroll
        for (int p = 0; p < 8; p++) acc[s][p] = (f32x4)0.f;
    int dsw = row & 7;
    const char* bE = (const char*)Eb + ((size_t)b * M + w * 128 + row) * 256;
    const float* cdD0 = cd + ((size_t)b * N + n0 + kg * 4) * M + w * 128 + row;
    const float* nfD0 = ninf + ((size_t)b * N + n0 + kg * 4) * M + w * 128 + row;
    const float* cdD1 = cdD0 + (size_t)16 * M;
    const float* nfD1 = nfD0 + (size_t)16 * M;
    s16x8 EF[4];
    float cdv[2][4], nfv[2][4];
#define LOAD_E1(pt)                                                              \
    EF[0] = *(const s16x8*)(bE + (size_t)(pt) * 4096 + ((0 + kg) ^ dsw) * 16);   \
    EF[1] = *(const s16x8*)(bE + (size_t)(pt) * 4096 + ((4 + kg) ^ dsw) * 16);   \
    EF[2] = *(const s16x8*)(bE + (size_t)(pt) * 4096 + ((8 + kg) ^ dsw) * 16);   \
    EF[3] = *(const s16x8*)(bE + (size_t)(pt) * 4096 + ((12 + kg) ^ dsw) * 16);
#define LOAD_CN(pt)                                                              \
    _Pragma("unroll")                                                            \
    for (int r = 0; r < 4; r++) {                                                \
        cdv[0][r] = cdD0[(size_t)r * M + (pt) * 16];                             \
        nfv[0][r] = nfD0[(size_t)r * M + (pt) * 16];                             \
        cdv[1][r] = cdD1[(size_t)r * M + (pt) * 16];                             \
        nfv[1][r] = nfD1[(size_t)r * M + (pt) * 16];                             \
    }

    LOAD_E1(0)
    LOAD_CN(0)

#pragma unroll
    for (int p = 0; p < 8; p++) {
#pragma unroll
        for (int es = 0; es < 4; es++) {
            s16x8 a0 = *(const s16x8*)(afb + (size_t)row * 272 + es * 64 + kg * 16);
            s16x8 a1 = *(const s16x8*)(afb + (size_t)(16 + row) * 272 + es * 64 + kg * 16);
            acc[0][p] = MFMA16(a0, EF[es], acc[0][p]);
            acc[1][p] = MFMA16(a1, EF[es], acc[1][p]);
        }
        if (p <= 6) { LOAD_E1(p + 1) }       // WAR after MFMAs
        // bias + tanh + mask
#pragma unroll
        for (int s = 0; s < 2; s++)
#pragma unroll
            for (int r = 0; r < 4; r++) {
                acc[s][p][r] = 10.f * fast_tanh(fmaf(acc[s][p][r], invs, -a2ls * cdv[s][r]))
                             + nfv[s][r];
            }
        if (p <= 6) { LOAD_CN(p + 1) }       // WAR after bias consumed
    }

    // ===== softmax over m =====
    float mx[2][4], sm[2][4];
#pragma unroll
    for (int s = 0; s < 2; s++)
#pragma unroll
        for (int r = 0; r < 4; r++) {
            float m = acc[s][0][r];
#pragma unroll
            for (int p = 1; p < 8; p++) m = fmaxf(m, acc[s][p][r]);
#pragma unroll
            for (int sh = 1; sh < 16; sh <<= 1) m = fmaxf(m, __shfl_xor(m, sh, 64));
            mx[s][r] = m;
        }
    if (row == 0) {
#pragma unroll
        for (int s = 0; s < 2; s++)
#pragma unroll
            for (int r = 0; r < 4; r++) redm[s * 16 + kg * 4 + r][w] = mx[s][r];
    }
    __syncthreads();
#pragma unroll
    for (int s = 0; s < 2; s++)
#pragma unroll
        for (int r = 0; r < 4; r++) {
            int nl = s * 16 + kg * 4 + r;
            float m = fmaxf(fmaxf(redm[nl][0], redm[nl][1]),
                            fmaxf(redm[nl][2], redm[nl][3]));
            float sum = 0.f;
#pragma unroll
            for (int p = 0; p < 8; p++) {
                float e = __expf(acc[s][p][r] - m);
                acc[s][p][r] = e;
                sum += e;
            }
#pragma unroll
            for (int sh = 1; sh < 16; sh <<= 1) sum += __shfl_xor(sum, sh, 64);
            sm[s][r] = sum;
        }
    if (row == 0) {
#pragma unroll
        for (int s = 0; s < 2; s++)
#pragma unroll
            for (int r = 0; r < 4; r++) reds[s * 16 + kg * 4 + r][w] = sm[s][r];
    }
    __syncthreads();
#pragma unroll
    for (int s = 0; s < 2; s++)
#pragma unroll
        for (int r = 0; r < 4; r++) {
            int nl = s * 16 + kg * 4 + r;
            float inv = 1.f / (reds[nl][0] + reds[nl][1] + reds[nl][2] + reds[nl][3]);
            size_t ro = ((size_t)b * N + n0 + nl) * M + (size_t)w * 128 + row;
#pragma unroll
            for (int p = 0; p < 8; p++) {
                out[ro + p * 16] = acc[s][p][r] * inv;
            }
        }
}

extern "C" void kernel_launch(void* const* d_in, const int* in_sizes, int n_in,
                              void* d_out, int out_size, void* d_ws, size_t ws_size,
                              hipStream_t stream) {
    const float* encl  = (const float*)d_in[0];
    const float* loadv = (const float*)d_in[1];
    const float* cdist = (const float*)d_in[2];
    const float* ls    = (const float*)d_in[3];
    const float* ninf  = (const float*)d_in[4];
    const float* enc   = (const float*)d_in[5];
    const float* Wq    = (const float*)d_in[6];
    const float* Wk    = (const float*)d_in[7];
    const float* Wv    = (const float*)d_in[8];
    const float* a1    = (const float*)d_in[9];
    const float* a2    = (const float*)d_in[10];
    char* ws = (char*)d_ws;
    unsigned short* EKb     = (unsigned short*)(ws);                    // 16.8 MB
    unsigned short* EKVb    = (unsigned short*)(ws + 16777216);         // 16.8 MB
    unsigned short* Eb      = (unsigned short*)(ws + 33554432);         // 16.8 MB
    unsigned short* Wk_hi   = (unsigned short*)(ws + 50331648);
    unsigned short* Wk_lo   = (unsigned short*)(ws + 50331648 + 32768);
    unsigned short* Wv_hi   = (unsigned short*)(ws + 50331648 + 65536);
    unsigned short* Wv_lo   = (unsigned short*)(ws + 50331648 + 98304);
    unsigned short* Wq_hi   = (unsigned short*)(ws + 50331648 + 131072);
    unsigned short* Wq_lo   = (unsigned short*)(ws + 50331648 + 163840);
    float* out = (float*)d_out;

    k_prep_w<<<192, 256, 0, stream>>>(Wk, Wv, Wq, Wk_hi, Wk_lo, Wv_hi, Wv_lo, Wq_hi, Wq_lo);
    k_kv<<<dim3(8, 128), 256, 0, stream>>>(enc, Wk_hi, Wk_lo, Wv_hi, Wv_lo, EKb, EKVb, Eb);
    k_fused<<<2048, 256, 0, stream>>>(encl, loadv, Wq, Wq_hi, Wq_lo,
                                      cdist, ninf, EKVb, EKb, Eb,
                                      a1, a2, ls, out);
}

// Round 19
// 324.845 us; speedup vs baseline: 2.3288x; 1.0037x over previous
//
#include <hip/hip_runtime.h>
#include <math.h>

#define B 128
#define N 512
#define M 512
#define D 128

typedef __attribute__((ext_vector_type(8))) short s16x8;
typedef __attribute__((ext_vector_type(4))) short s16x4;
typedef __attribute__((ext_vector_type(4))) float f32x4;

#define MFMA16(a, b, c) __builtin_amdgcn_mfma_f32_16x16x32_bf16(a, b, c, 0, 0, 0)

__device__ __forceinline__ float fast_tanh(float x) {
    x = fminf(fmaxf(x, -15.f), 15.f);
    float E = __expf(2.f * x);
    return 1.f - 2.f / (E + 1.f);
}

__device__ __forceinline__ unsigned short bf16rne(float x) {
    unsigned u = __float_as_uint(x);
    return (unsigned short)((u + 0x7FFF + ((u >> 16) & 1)) >> 16);
}

__device__ __forceinline__ void fsplit(float x, short& h, short& l) {
    unsigned u = __float_as_uint(x);
    h = (short)(u >> 16);
    float fh = __uint_as_float(u & 0xffff0000u);
    l = (short)(__float_as_uint(x - fh) >> 16);
}

__device__ __forceinline__ void fsplit8(float4 x0, float4 x1, s16x8& h, s16x8& l) {
    short a, b;
    fsplit(x0.x, a, b); h[0] = a; l[0] = b;
    fsplit(x0.y, a, b); h[1] = a; l[1] = b;
    fsplit(x0.z, a, b); h[2] = a; l[2] = b;
    fsplit(x0.w, a, b); h[3] = a; l[3] = b;
    fsplit(x1.x, a, b); h[4] = a; l[4] = b;
    fsplit(x1.y, a, b); h[5] = a; l[5] = b;
    fsplit(x1.z, a, b); h[6] = a; l[6] = b;
    fsplit(x1.w, a, b); h[7] = a; l[7] = b;
}

// EB = exp(-a1ls*cd + ninf) -> single bf16 RNE
__device__ __forceinline__ void ebpack(float4 c0, float4 c1, float4 f0, float4 f1,
                                       float a1ls, s16x8& a) {
    a[0] = (short)bf16rne(__expf(fmaf(-a1ls, c0.x, f0.x)));
    a[1] = (short)bf16rne(__expf(fmaf(-a1ls, c0.y, f0.y)));
    a[2] = (short)bf16rne(__expf(fmaf(-a1ls, c0.z, f0.z)));
    a[3] = (short)bf16rne(__expf(fmaf(-a1ls, c0.w, f0.w)));
    a[4] = (short)bf16rne(__expf(fmaf(-a1ls, c1.x, f1.x)));
    a[5] = (short)bf16rne(__expf(fmaf(-a1ls, c1.y, f1.y)));
    a[6] = (short)bf16rne(__expf(fmaf(-a1ls, c1.z, f1.z)));
    a[7] = (short)bf16rne(__expf(fmaf(-a1ls, c1.w, f1.w)));
}

__global__ void k_prep_w(const float* __restrict__ Wk, const float* __restrict__ Wv,
                         const float* __restrict__ Wq,
                         unsigned short* __restrict__ Wk_hi, unsigned short* __restrict__ Wk_lo,
                         unsigned short* __restrict__ Wv_hi, unsigned short* __restrict__ Wv_lo,
                         unsigned short* __restrict__ Wq_hi, unsigned short* __restrict__ Wq_lo) {
    int i = blockIdx.x * 256 + threadIdx.x;  // 0..49151
    short h, l;
    if (i < 16384) {
        fsplit(Wk[i], h, l); Wk_hi[i] = (unsigned short)h; Wk_lo[i] = (unsigned short)l;
    } else if (i < 32768) {
        int j = i - 16384;
        fsplit(Wv[j], h, l); Wv_hi[j] = (unsigned short)h; Wv_lo[j] = (unsigned short)l;
    } else {
        int j = i - 32768; int e = j >> 7, d = j & 127;
        fsplit(Wq[e * 129 + d], h, l); Wq_hi[j] = (unsigned short)h; Wq_lo[j] = (unsigned short)l;
    }
}

// k = enc@Wk^T, v = enc@Wv^T; store bf16-RNE EK, EK*V as [b][e][m] (m-chunk c at
// c ^ (e&3) within 32-m group). Also emits Eb = bf16(enc) [b][m][e] (e-chunk c at
// c ^ (m&7)).
__global__ __launch_bounds__(256) void k_kv(const float* __restrict__ enc,
        const unsigned short* __restrict__ Wk_hi, const unsigned short* __restrict__ Wk_lo,
        const unsigned short* __restrict__ Wv_hi, const unsigned short* __restrict__ Wv_lo,
        unsigned short* __restrict__ EKb, unsigned short* __restrict__ EKVb,
        unsigned short* __restrict__ Eb) {
    int b = blockIdx.y;
    int wave = threadIdx.x >> 6, lane = threadIdx.x & 63;
    int row = lane & 15, kg = lane >> 4;
    int m0 = blockIdx.x * 64 + wave * 16;
    f32x4 acc[16];
#pragma unroll
    for (int i = 0; i < 16; i++) acc[i] = (f32x4)0.f;
    const float* ap = enc + ((size_t)b * M + m0 + row) * D + kg * 8;
    int menc = m0 + row;
#pragma unroll
    for (int ks = 0; ks < 4; ks++) {
        float4 x0 = *(const float4*)(ap + ks * 32);
        float4 x1 = *(const float4*)(ap + ks * 32 + 4);
        s16x8 ah, al;
        fsplit8(x0, x1, ah, al);
        s16x8 ev;
        ev[0] = (short)bf16rne(x0.x); ev[1] = (short)bf16rne(x0.y);
        ev[2] = (short)bf16rne(x0.z); ev[3] = (short)bf16rne(x0.w);
        ev[4] = (short)bf16rne(x1.x); ev[5] = (short)bf16rne(x1.y);
        ev[6] = (short)bf16rne(x1.z); ev[7] = (short)bf16rne(x1.w);
        int c = ks * 4 + kg;
        *(s16x8*)(Eb + ((size_t)b * M + menc) * D + (size_t)((c ^ (menc & 7)) * 8)) = ev;
        int wb = ks * 32 + kg * 8;
#pragma unroll
        for (int ct = 0; ct < 8; ct++) {
            int e = ct * 16 + row;
            s16x8 bh = *(const s16x8*)(Wk_hi + e * D + wb);
            s16x8 bl = *(const s16x8*)(Wk_lo + e * D + wb);
            acc[ct] = MFMA16(ah, bh, acc[ct]);
            acc[ct] = MFMA16(al, bh, acc[ct]);
            acc[ct] = MFMA16(ah, bl, acc[ct]);
            bh = *(const s16x8*)(Wv_hi + e * D + wb);
            bl = *(const s16x8*)(Wv_lo + e * D + wb);
            acc[8 + ct] = MFMA16(ah, bh, acc[8 + ct]);
            acc[8 + ct] = MFMA16(al, bh, acc[8 + ct]);
            acc[8 + ct] = MFMA16(ah, bl, acc[8 + ct]);
        }
    }
#pragma unroll
    for (int ct = 0; ct < 8; ct++) {
        int e = ct * 16 + row;
        s16x4 kb, vb;
#pragma unroll
        for (int r = 0; r < 4; r++) {
            float ek = __expf(acc[ct][r]);
            float ev = ek * acc[8 + ct][r];
            kb[r] = (short)bf16rne(ek);
            vb[r] = (short)bf16rne(ev);
        }
        int m = m0 + kg * 4;
        int chunk = (m & 31) >> 3;
        int p = chunk ^ (e & 3);
        size_t o = ((size_t)b * D + e) * M + (size_t)(m & ~31) + p * 8 + (m & 7);
        *(s16x4*)(EKb + o) = kb;
        *(s16x4*)(EKVb + o) = vb;
    }
}

// MEGA-FUSED: q + numden + aafm + score + softmax. Direct L2 loads.
// Issue-order fix: B-operands issued BEFORE younger raw loads (in-order vmcnt
// retirement never full-drains). Raw cd/ninf depth-2; tile t raw lives in slot t&1.
__global__ __launch_bounds__(256, 3) void k_fused(
        const float* __restrict__ encl, const float* __restrict__ loadv,
        const float* __restrict__ Wq,
        const unsigned short* __restrict__ Wq_hi, const unsigned short* __restrict__ Wq_lo,
        const float* __restrict__ cd, const float* __restrict__ ninf,
        const unsigned short* __restrict__ EKVb, const unsigned short* __restrict__ EKb,
        const unsigned short* __restrict__ Eb,
        const float* __restrict__ a1p, const float* __restrict__ a2p,
        const float* __restrict__ lsp, float* __restrict__ out) {
    int o = blockIdx.x;
    int xcd = o & 7, j = o >> 3;       // j 0..255
    int b = ((j >> 4) << 3) + xcd;     // 16 b's per XCD (same-b co-resident)
    int nb = j & 15;
    int n0 = nb * 32;
    int w = threadIdx.x >> 6, lane = threadIdx.x & 63;
    int row = lane & 15, kg = lane >> 4;
    __shared__ __align__(16) char afb[32 * 272];   // aafm bounce, stride 272 B
    __shared__ float redm[32][4], reds[32][4];
    float a1ls = a1p[0] * lsp[0];
    float a2ls = a2p[0] * lsp[0];
    const float invs = 0.08838834764831845f;  // 1/sqrt(128)

    // ===== Phase A: q-pass; sigmoid packed to bf16 pairs =====
    f32x4 sqa[2][2];
#pragma unroll
    for (int s = 0; s < 2; s++)
#pragma unroll
        for (int ct = 0; ct < 2; ct++) sqa[s][ct] = (f32x4)0.f;
#pragma unroll
    for (int s = 0; s < 2; s++) {
        const float* ap = encl + ((size_t)b * N + n0 + s * 16 + row) * D + kg * 8;
#pragma unroll
        for (int ks = 0; ks < 4; ks++) {
            float4 x0 = *(const float4*)(ap + ks * 32);
            float4 x1 = *(const float4*)(ap + ks * 32 + 4);
            s16x8 ah, al;
            fsplit8(x0, x1, ah, al);
            int wqo = ks * 32 + kg * 8;
#pragma unroll
            for (int ct = 0; ct < 2; ct++) {
                int e = w * 32 + ct * 16 + row;
                s16x8 bh = *(const s16x8*)(Wq_hi + e * D + wqo);
                s16x8 bl = *(const s16x8*)(Wq_lo + e * D + wqo);
                sqa[s][ct] = MFMA16(ah, bh, sqa[s][ct]);
                sqa[s][ct] = MFMA16(al, bh, sqa[s][ct]);
                sqa[s][ct] = MFMA16(ah, bl, sqa[s][ct]);
            }
        }
    }
    unsigned sqp[2][2][2];   // [s][ct][rpair]: 2 x bf16 sigmoid
#pragma unroll
    for (int s = 0; s < 2; s++)
#pragma unroll
        for (int ct = 0; ct < 2; ct++) {
            int e = w * 32 + ct * 16 + row;
            float wcol = Wq[e * 129 + 128];
#pragma unroll
            for (int rp = 0; rp < 2; rp++) {
                int n = n0 + s * 16 + kg * 4 + rp * 2;
                float q0 = sqa[s][ct][rp * 2] + loadv[(size_t)b * N + n] * wcol;
                float q1 = sqa[s][ct][rp * 2 + 1] + loadv[(size_t)b * N + n + 1] * wcol;
                unsigned lo = bf16rne(1.f / (1.f + __expf(-q0)));
                unsigned hi = bf16rne(1.f / (1.f + __expf(-q1)));
                sqp[s][ct][rp] = lo | (hi << 16);
            }
        }

    // ===== Phase B: num/den; depth-2 raw slots; B issued before raw =====
    f32x4 accN[2][2], accD[2][2];
#pragma unroll
    for (int s = 0; s < 2; s++)
#pragma unroll
        for (int i = 0; i < 2; i++) { accN[s][i] = (f32x4)0.f; accD[s][i] = (f32x4)0.f; }
    const float* cdp0 = cd + ((size_t)b * N + n0 + row) * M + kg * 8;
    const float* nfp0 = ninf + ((size_t)b * N + n0 + row) * M + kg * 8;
    const float* cdp1 = cdp0 + (size_t)16 * M;
    const float* nfp1 = nfp0 + (size_t)16 * M;
    int swo = (kg ^ (row & 3)) << 4;   // bytes
    const char* bVp[2]; const char* bKp[2];
#pragma unroll
    for (int ct = 0; ct < 2; ct++) {
        int e = w * 32 + ct * 16 + row;
        bVp[ct] = (const char*)EKVb + (((size_t)b * D + e) * M) * 2 + swo;
        bKp[ct] = (const char*)EKb  + (((size_t)b * D + e) * M) * 2 + swo;
    }
    float4 Rc[2][2][2], Rf[2][2][2];   // [slot][n-set][half]; tile t -> slot t&1
    s16x8 EA[2][2];                    // [parity][n-set]
    s16x8 BV[2][2], BK[2][2];          // [parity][ct]
#define RAWLOAD(sl, mt)                                                          \
    Rc[sl][0][0] = *(const float4*)(cdp0 + (mt) * 32);                           \
    Rc[sl][0][1] = *(const float4*)(cdp0 + (mt) * 32 + 4);                       \
    Rf[sl][0][0] = *(const float4*)(nfp0 + (mt) * 32);                           \
    Rf[sl][0][1] = *(const float4*)(nfp0 + (mt) * 32 + 4);                       \
    Rc[sl][1][0] = *(const float4*)(cdp1 + (mt) * 32);                           \
    Rc[sl][1][1] = *(const float4*)(cdp1 + (mt) * 32 + 4);                       \
    Rf[sl][1][0] = *(const float4*)(nfp1 + (mt) * 32);                           \
    Rf[sl][1][1] = *(const float4*)(nfp1 + (mt) * 32 + 4);
#define EBCONV(p, sl)                                                            \
    ebpack(Rc[sl][0][0], Rc[sl][0][1], Rf[sl][0][0], Rf[sl][0][1], a1ls, EA[p][0]); \
    ebpack(Rc[sl][1][0], Rc[sl][1][1], Rf[sl][1][0], Rf[sl][1][1], a1ls, EA[p][1]);
#define LOADB(p, mt)                                                             \
    BV[p][0] = *(const s16x8*)(bVp[0] + (mt) * 64);                              \
    BV[p][1] = *(const s16x8*)(bVp[1] + (mt) * 64);                              \
    BK[p][0] = *(const s16x8*)(bKp[0] + (mt) * 64);                              \
    BK[p][1] = *(const s16x8*)(bKp[1] + (mt) * 64);

    // prologue: B first (needed soonest), then raws; converts before the loop.
    // After this: EA[0]=tile0, EA[1]=tile1, slot0=tile2 raw, B[0]=tile0, B[1]=tile1.
    LOADB(0, 0) LOADB(1, 1)
    RAWLOAD(0, 0) RAWLOAD(1, 1)
    EBCONV(0, 0)
    RAWLOAD(0, 2)      // slot0 free after EBCONV(0,0); holds tile 2
    EBCONV(1, 1)       // EA[1] <- tile 1 (slot1)

#pragma unroll
    for (int mt = 0; mt < 16; mt++) {
        int p = mt & 1;
        // MFMA on tile mt: waits B(mt); younger raw(mt+1), B(mt+1), raw(mt+2) in flight
#pragma unroll
        for (int ct = 0; ct < 2; ct++) {
            accN[0][ct] = MFMA16(EA[p][0], BV[p][ct], accN[0][ct]);
            accN[1][ct] = MFMA16(EA[p][1], BV[p][ct], accN[1][ct]);
            accD[0][ct] = MFMA16(EA[p][0], BK[p][ct], accD[0][ct]);
            accD[1][ct] = MFMA16(EA[p][1], BK[p][ct], accD[1][ct]);
        }
        if (mt <= 13) { LOADB(p, mt + 2) }       // B for tile mt+2 (slot p free)
        if (mt <= 13) { EBCONV(p, p) }           // EA[p] <- tile mt+2 (slot (mt+2)&1 = p)
        if (mt <= 12) { RAWLOAD((mt + 1) & 1, mt + 3) }  // slot (mt+3)&1 free after its EBCONV
    }

    // ===== Phase C: aafm = sq*nan_to_num(num/den) -> bf16 into LDS =====
#pragma unroll
    for (int s = 0; s < 2; s++)
#pragma unroll
        for (int ct = 0; ct < 2; ct++) {
            int e = w * 32 + ct * 16 + row;
#pragma unroll
            for (int r = 0; r < 4; r++) {
                int nl = s * 16 + kg * 4 + r;
                float num = accN[s][ct][r], den = accD[s][ct][r];
                float ww = (den != 0.f) ? num / den : 0.f;
                unsigned us = (r & 1) ? (sqp[s][ct][r >> 1] >> 16)
                                      : (sqp[s][ct][r >> 1] & 0xffffu);
                float sq = __uint_as_float(us << 16);
                *(unsigned short*)(afb + nl * 272 + e * 2) = bf16rne(sq * ww);
            }
        }
    __syncthreads();

    // ===== Phase D: score; A-frags from afb; E before CN in issue order =====
    f32x4 acc[2][8];
#pragma unroll
    for (int s = 0; s < 2; s++)
#pragma unroll
        for (int p = 0; p < 8; p++) acc[s][p] = (f32x4)0.f;
    int dsw = row & 7;
    const char* bE = (const char*)Eb + ((size_t)b * M + w * 128 + row) * 256;
    const float* cdD0 = cd + ((size_t)b * N + n0 + kg * 4) * M + w * 128 + row;
    const float* nfD0 = ninf + ((size_t)b * N + n0 + kg * 4) * M + w * 128 + row;
    const float* cdD1 = cdD0 + (size_t)16 * M;
    const float* nfD1 = nfD0 + (size_t)16 * M;
    s16x8 EF[4];
    float cdv[2][4], nfv[2][4];
#define LOAD_E1(pt)                                                              \
    EF[0] = *(const s16x8*)(bE + (size_t)(pt) * 4096 + ((0 + kg) ^ dsw) * 16);   \
    EF[1] = *(const s16x8*)(bE + (size_t)(pt) * 4096 + ((4 + kg) ^ dsw) * 16);   \
    EF[2] = *(const s16x8*)(bE + (size_t)(pt) * 4096 + ((8 + kg) ^ dsw) * 16);   \
    EF[3] = *(const s16x8*)(bE + (size_t)(pt) * 4096 + ((12 + kg) ^ dsw) * 16);
#define LOAD_CN(pt)                                                              \
    _Pragma("unroll")                                                            \
    for (int r = 0; r < 4; r++) {                                                \
        cdv[0][r] = cdD0[(size_t)r * M + (pt) * 16];                             \
        nfv[0][r] = nfD0[(size_t)r * M + (pt) * 16];                             \
        cdv[1][r] = cdD1[(size_t)r * M + (pt) * 16];                             \
        nfv[1][r] = nfD1[(size_t)r * M + (pt) * 16];                             \
    }

    LOAD_E1(0)
    LOAD_CN(0)

#pragma unroll
    for (int p = 0; p < 8; p++) {
#pragma unroll
        for (int es = 0; es < 4; es++) {
            s16x8 a0 = *(const s16x8*)(afb + (size_t)row * 272 + es * 64 + kg * 16);
            s16x8 a1 = *(const s16x8*)(afb + (size_t)(16 + row) * 272 + es * 64 + kg * 16);
            acc[0][p] = MFMA16(a0, EF[es], acc[0][p]);
            acc[1][p] = MFMA16(a1, EF[es], acc[1][p]);
        }
        if (p <= 6) { LOAD_E1(p + 1) }       // WAR after MFMAs; E before CN
        // bias + tanh + mask
#pragma unroll
        for (int s = 0; s < 2; s++)
#pragma unroll
            for (int r = 0; r < 4; r++) {
                acc[s][p][r] = 10.f * fast_tanh(fmaf(acc[s][p][r], invs, -a2ls * cdv[s][r]))
                             + nfv[s][r];
            }
        if (p <= 6) { LOAD_CN(p + 1) }       // WAR after bias consumed
    }

    // ===== softmax over m =====
    float mx[2][4], sm[2][4];
#pragma unroll
    for (int s = 0; s < 2; s++)
#pragma unroll
        for (int r = 0; r < 4; r++) {
            float m = acc[s][0][r];
#pragma unroll
            for (int p = 1; p < 8; p++) m = fmaxf(m, acc[s][p][r]);
#pragma unroll
            for (int sh = 1; sh < 16; sh <<= 1) m = fmaxf(m, __shfl_xor(m, sh, 64));
            mx[s][r] = m;
        }
    if (row == 0) {
#pragma unroll
        for (int s = 0; s < 2; s++)
#pragma unroll
            for (int r = 0; r < 4; r++) redm[s * 16 + kg * 4 + r][w] = mx[s][r];
    }
    __syncthreads();
#pragma unroll
    for (int s = 0; s < 2; s++)
#pragma unroll
        for (int r = 0; r < 4; r++) {
            int nl = s * 16 + kg * 4 + r;
            float m = fmaxf(fmaxf(redm[nl][0], redm[nl][1]),
                            fmaxf(redm[nl][2], redm[nl][3]));
            float sum = 0.f;
#pragma unroll
            for (int p = 0; p < 8; p++) {
                float e = __expf(acc[s][p][r] - m);
                acc[s][p][r] = e;
                sum += e;
            }
#pragma unroll
            for (int sh = 1; sh < 16; sh <<= 1) sum += __shfl_xor(sum, sh, 64);
            sm[s][r] = sum;
        }
    if (row == 0) {
#pragma unroll
        for (int s = 0; s < 2; s++)
#pragma unroll
            for (int r = 0; r < 4; r++) reds[s * 16 + kg * 4 + r][w] = sm[s][r];
    }
    __syncthreads();
#pragma unroll
    for (int s = 0; s < 2; s++)
#pragma unroll
        for (int r = 0; r < 4; r++) {
            int nl = s * 16 + kg * 4 + r;
            float inv = 1.f / (reds[nl][0] + reds[nl][1] + reds[nl][2] + reds[nl][3]);
            size_t ro = ((size_t)b * N + n0 + nl) * M + (size_t)w * 128 + row;
#pragma unroll
            for (int p = 0; p < 8; p++) {
                out[ro + p * 16] = acc[s][p][r] * inv;
            }
        }
}

extern "C" void kernel_launch(void* const* d_in, const int* in_sizes, int n_in,
                              void* d_out, int out_size, void* d_ws, size_t ws_size,
                              hipStream_t stream) {
    const float* encl  = (const float*)d_in[0];
    const float* loadv = (const float*)d_in[1];
    const float* cdist = (const float*)d_in[2];
    const float* ls    = (const float*)d_in[3];
    const float* ninf  = (const float*)d_in[4];
    const float* enc   = (const float*)d_in[5];
    const float* Wq    = (const float*)d_in[6];
    const float* Wk    = (const float*)d_in[7];
    const float* Wv    = (const float*)d_in[8];
    const float* a1    = (const float*)d_in[9];
    const float* a2    = (const float*)d_in[10];
    char* ws = (char*)d_ws;
    unsigned short* EKb     = (unsigned short*)(ws);                    // 16.8 MB
    unsigned short* EKVb    = (unsigned short*)(ws + 16777216);         // 16.8 MB
    unsigned short* Eb      = (unsigned short*)(ws + 33554432);         // 16.8 MB
    unsigned short* Wk_hi   = (unsigned short*)(ws + 50331648);
    unsigned short* Wk_lo   = (unsigned short*)(ws + 50331648 + 32768);
    unsigned short* Wv_hi   = (unsigned short*)(ws + 50331648 + 65536);
    unsigned short* Wv_lo   = (unsigned short*)(ws + 50331648 + 98304);
    unsigned short* Wq_hi   = (unsigned short*)(ws + 50331648 + 131072);
    unsigned short* Wq_lo   = (unsigned short*)(ws + 50331648 + 163840);
    float* out = (float*)d_out;

    k_prep_w<<<192, 256, 0, stream>>>(Wk, Wv, Wq, Wk_hi, Wk_lo, Wv_hi, Wv_lo, Wq_hi, Wq_lo);
    k_kv<<<dim3(8, 128), 256, 0, stream>>>(enc, Wk_hi, Wk_lo, Wv_hi, Wv_lo, EKb, EKVb, Eb);
    k_fused<<<2048, 256, 0, stream>>>(encl, loadv, Wq, Wq_hi, Wq_lo,
                                      cdist, ninf, EKVb, EKb, Eb,
                                      a1, a2, ls, out);
}